// Round 1
// baseline (600.936 us; speedup 1.0000x reference)
//
#include <hip/hip_runtime.h>
#include <stdint.h>

// ---------------------------------------------------------------------------
// MixedSparseSingleLayerWithGate: NF4-dequant QLoRA transformer layer, MI355X.
// B=1 S=2048 D=1024 F=2816 H=16 DH=64 R=16 BLK=64.
//
// Strategy (round 1, correctness-first):
//  - All matmuls in bf16 MFMA (16x16x32), fp32 accum. Tolerance is bf16-level.
//  - LoRA folded into GEMM as K-extension: A_ext = [h | T_q | T_k | ...],
//    B_ext = [W_dequant | lb^T slots], so one GEMM does x@W^T + (x@la)@lb.
//  - qkv packed (N=3072), gate+up packed (N=5632).
//  - o-proj GEMM fuses residual (x1 = x + o); down GEMM fuses (out = x1+down).
//  - Attention: flash-style, 1 block per (head, 64 q rows); V pre-transposed.
// ---------------------------------------------------------------------------

#define Sq   2048
#define Dm   1024
#define Fm   2816
#define Hh   16
#define KE1  1088   // h_ext stride / qkv GEMM K   (1024 + 16*3 + 16 pad)
#define KE2  1056   // o & gate/up GEMM K          (1024 + 16 + 16)
#define KE3  2848   // down GEMM K                 (2816 + 16 + 16)
#define NQKV 3072
#define NGU  5632

typedef short bf16x8 __attribute__((ext_vector_type(8)));
typedef float f32x4  __attribute__((ext_vector_type(4)));

__constant__ float NF4_LUT[16] = {
    -1.0f, -0.6961928009986877f, -0.5250730514526367f, -0.39491748809814453f,
    -0.28444138169288635f, -0.18477343022823334f, -0.09105003625154495f, 0.0f,
    0.07958029955625534f, 0.16093020141124725f, 0.24611230194568634f,
    0.33791524171829224f, 0.44070982933044434f, 0.5626170039176941f,
    0.7229568362236023f, 1.0f};

__device__ inline unsigned short f2bf(float f) {
    union { float f; uint32_t u; } v; v.f = f;
    uint32_t u = v.u;
    return (unsigned short)((u + 0x7FFFu + ((u >> 16) & 1u)) >> 16);
}
__device__ inline float bf2f(unsigned short h) {
    union { uint32_t u; float f; } v; v.u = ((uint32_t)h) << 16;
    return v.f;
}

// --------------------------- rmsnorm -> bf16 ext -----------------------------
// one block per row; writes h_ext[s, 0:1024] = rmsnorm, zeros cols 1024..1087
__global__ __launch_bounds__(256) void rmsnorm_ext(
    const float* __restrict__ X, const float* __restrict__ W,
    unsigned short* Hout, int ldh)
{
    int s = blockIdx.x, tid = threadIdx.x;
    const float4 v = *(const float4*)(X + (size_t)s * Dm + tid * 4);
    float ss = v.x * v.x + v.y * v.y + v.z * v.z + v.w * v.w;
#pragma unroll
    for (int m = 1; m < 64; m <<= 1) ss += __shfl_xor(ss, m);
    __shared__ float red[4];
    int lane = tid & 63, wave = tid >> 6;
    if (lane == 0) red[wave] = ss;
    __syncthreads();
    float scale = rsqrtf((red[0] + red[1] + red[2] + red[3]) * (1.0f / Dm) + 1e-10f);
    const float4 w = *(const float4*)(W + tid * 4);
    alignas(8) unsigned short o[4];
    o[0] = f2bf(v.x * scale * w.x);
    o[1] = f2bf(v.y * scale * w.y);
    o[2] = f2bf(v.z * scale * w.z);
    o[3] = f2bf(v.w * scale * w.w);
    *(ushort4*)(Hout + (size_t)s * ldh + tid * 4) = *(ushort4*)o;
    if (tid < 64) Hout[(size_t)s * ldh + Dm + tid] = 0;   // zero ext tail
}

// ------------------------------ T = A @ la ----------------------------------
// one block per row s; writes bf16 T into A_ext cols [toff,toff+16),
// optionally zeros cols [zoff, zoff+zn).
__global__ __launch_bounds__(256) void lora_T(
    const unsigned short* Aext, int lda, int K,
    const float* __restrict__ la, int toff, int zoff, int zn)
{
    int s = blockIdx.x, tid = threadIdx.x;
    float acc[16];
#pragma unroll
    for (int r = 0; r < 16; ++r) acc[r] = 0.f;
    const unsigned short* arow = Aext + (size_t)s * lda;
    for (int k = tid; k < K; k += 256) {
        float h = bf2f(arow[k]);
        const float4* lp = (const float4*)(la + (size_t)k * 16);
        float4 l0 = lp[0], l1 = lp[1], l2 = lp[2], l3 = lp[3];
        acc[0]  += h * l0.x; acc[1]  += h * l0.y; acc[2]  += h * l0.z; acc[3]  += h * l0.w;
        acc[4]  += h * l1.x; acc[5]  += h * l1.y; acc[6]  += h * l1.z; acc[7]  += h * l1.w;
        acc[8]  += h * l2.x; acc[9]  += h * l2.y; acc[10] += h * l2.z; acc[11] += h * l2.w;
        acc[12] += h * l3.x; acc[13] += h * l3.y; acc[14] += h * l3.z; acc[15] += h * l3.w;
    }
#pragma unroll
    for (int r = 0; r < 16; ++r)
#pragma unroll
        for (int m = 1; m < 64; m <<= 1) acc[r] += __shfl_xor(acc[r], m);
    __shared__ float red[4][16];
    int lane = tid & 63, wave = tid >> 6;
    if (lane == 0)
#pragma unroll
        for (int r = 0; r < 16; ++r) red[wave][r] = acc[r];
    __syncthreads();
    unsigned short* drow = (unsigned short*)Aext + (size_t)s * lda;
    if (tid < 16)
        drow[toff + tid] = f2bf(red[0][tid] + red[1][tid] + red[2][tid] + red[3][tid]);
    if (zn > 0 && tid >= 16 && tid < 16 + zn) drow[zoff + (tid - 16)] = 0;
}

// --------------------- NF4 dequant -> bf16, K-extended ----------------------
// W_ext[n, 0:K) = LUT[code]*absmax ; W_ext[n, toff:toff+16) = lb[:,n] ; else 0
__global__ __launch_bounds__(256) void dequant_ext(
    const int* __restrict__ codes, const float* __restrict__ absmax,
    const float* __restrict__ lb, unsigned short* __restrict__ Wout,
    int Nproj, int K, int ldw, int toff)
{
    __shared__ float lut[16];
    if (threadIdx.x < 16) lut[threadIdx.x] = NF4_LUT[threadIdx.x];
    __syncthreads();
    int idx = blockIdx.x * 256 + threadIdx.x;
    int cpr = ldw >> 3;
    int n = idx / cpr;
    if (n >= Nproj) return;
    int c8 = (idx - n * cpr) * 8;
    alignas(16) unsigned short out[8];
    if (c8 < K) {
        size_t base = (size_t)n * K + c8;
        const int4* cp = (const int4*)(codes + base);
        int4 ca = cp[0], cb = cp[1];
        float am = absmax[base >> 6];
        out[0] = f2bf(lut[ca.x] * am); out[1] = f2bf(lut[ca.y] * am);
        out[2] = f2bf(lut[ca.z] * am); out[3] = f2bf(lut[ca.w] * am);
        out[4] = f2bf(lut[cb.x] * am); out[5] = f2bf(lut[cb.y] * am);
        out[6] = f2bf(lut[cb.z] * am); out[7] = f2bf(lut[cb.w] * am);
    } else {
        int r = c8 - toff;
#pragma unroll
        for (int i = 0; i < 8; ++i) out[i] = 0;
        if (r >= 0 && r < 16) {
#pragma unroll
            for (int i = 0; i < 8; ++i) out[i] = f2bf(lb[(size_t)(r + i) * Nproj + n]);
        }
    }
    *(uint4*)(Wout + (size_t)n * ldw + c8) = *(uint4*)out;
}

// ------------------------------- bf16 GEMM ----------------------------------
// C[M,N] = A[M,K](lda) * B[N,K](ldb)^T ; 128x128 tile, BK=32, 4 waves.
// mode bf16: Cb != null -> Cb[row*ldc+col] = bf16(acc)
// mode f32 : Cb == null -> Cf[row*ldc+col] = acc + Radd[row*ldc+col]
__global__ __launch_bounds__(256) void gemm_bf16(
    const unsigned short* __restrict__ A, int lda,
    const unsigned short* __restrict__ B, int ldb, int K,
    unsigned short* __restrict__ Cb, int ldc,
    float* __restrict__ Cf, const float* __restrict__ Radd)
{
    __shared__ __align__(16) unsigned short At[128 * 32];
    __shared__ __align__(16) unsigned short Bt[128 * 32];
    int tid = threadIdx.x;
    int lane = tid & 63, wave = tid >> 6;
    int lr = lane & 15, quad = lane >> 4;
    int wm = (wave >> 1) * 64, wn = (wave & 1) * 64;
    int row0 = blockIdx.y * 128, col0 = blockIdx.x * 128;
    f32x4 acc[4][4];
    f32x4 zero = {0.f, 0.f, 0.f, 0.f};
#pragma unroll
    for (int i = 0; i < 4; ++i)
#pragma unroll
        for (int j = 0; j < 4; ++j) acc[i][j] = zero;
    const unsigned short* Ab = A + (size_t)row0 * lda;
    const unsigned short* Bb = B + (size_t)col0 * ldb;
    int c0 = tid, c1 = tid + 256;
    int ar0 = c0 >> 2, ac0 = (c0 & 3) * 8;
    int ar1 = c1 >> 2, ac1 = (c1 & 3) * 8;
    for (int k0 = 0; k0 < K; k0 += 32) {
        uint4 av0 = *(const uint4*)(Ab + (size_t)ar0 * lda + k0 + ac0);
        uint4 av1 = *(const uint4*)(Ab + (size_t)ar1 * lda + k0 + ac1);
        uint4 bv0 = *(const uint4*)(Bb + (size_t)ar0 * ldb + k0 + ac0);
        uint4 bv1 = *(const uint4*)(Bb + (size_t)ar1 * ldb + k0 + ac1);
        __syncthreads();                       // prev-iter frag reads done
        *(uint4*)(At + c0 * 8) = av0;
        *(uint4*)(At + c1 * 8) = av1;
        *(uint4*)(Bt + c0 * 8) = bv0;
        *(uint4*)(Bt + c1 * 8) = bv1;
        __syncthreads();                       // staging visible
        bf16x8 af[4], bfr[4];
#pragma unroll
        for (int i = 0; i < 4; ++i)
            af[i] = *(const bf16x8*)(At + (wm + i * 16 + lr) * 32 + quad * 8);
#pragma unroll
        for (int j = 0; j < 4; ++j)
            bfr[j] = *(const bf16x8*)(Bt + (wn + j * 16 + lr) * 32 + quad * 8);
#pragma unroll
        for (int i = 0; i < 4; ++i)
#pragma unroll
            for (int j = 0; j < 4; ++j)
                acc[i][j] = __builtin_amdgcn_mfma_f32_16x16x32_bf16(af[i], bfr[j], acc[i][j], 0, 0, 0);
    }
#pragma unroll
    for (int i = 0; i < 4; ++i) {
        int rowb = row0 + wm + i * 16 + quad * 4;
#pragma unroll
        for (int j = 0; j < 4; ++j) {
            int col = col0 + wn + j * 16 + lr;
#pragma unroll
            for (int r = 0; r < 4; ++r) {
                float v = acc[i][j][r];
                size_t o = (size_t)(rowb + r) * ldc + col;
                if (Cb) Cb[o] = f2bf(v);
                else    Cf[o] = v + Radd[o];
            }
        }
    }
}

// ----------------------- rope + split q/k (scaled q) ------------------------
__global__ __launch_bounds__(256) void rope_split(
    const unsigned short* __restrict__ qkv,
    const float* __restrict__ cosT, const float* __restrict__ sinT,
    const int* __restrict__ pos,
    unsigned short* __restrict__ qb, unsigned short* __restrict__ kb)
{
    int idx = blockIdx.x * 256 + threadIdx.x;   // over 2048*1024
    int s = idx >> 10, col = idx & 1023, d = col & 63;
    int p = pos[s];
    float c = cosT[p * 64 + d], sn = sinT[p * 64 + d];
    int partner = (d < 32) ? (col + 32) : (col - 32);
    float sgn = (d < 32) ? -1.f : 1.f;
    const unsigned short* row = qkv + (size_t)s * NQKV;
    float q = bf2f(row[col]), q2 = bf2f(row[partner]);
    float k = bf2f(row[Dm + col]), k2 = bf2f(row[Dm + partner]);
    qb[idx] = f2bf((q * c + sgn * q2 * sn) * 0.125f);   // 1/sqrt(DH) folded in
    kb[idx] = f2bf(k * c + sgn * k2 * sn);
}

// -------------------- transpose V slice: vT[d, s] ---------------------------
__global__ __launch_bounds__(256) void vtrans(
    const unsigned short* __restrict__ qkv, unsigned short* __restrict__ vT)
{
    __shared__ __align__(16) unsigned short t[64][80];   // pad 16 keeps 16B align
    int bs = blockIdx.x * 64, bc = blockIdx.y * 64;
    int tid = threadIdx.x;
    for (int i = tid; i < 512; i += 256) {
        int r = i >> 3, c8 = (i & 7) * 8;
        *(uint4*)&t[r][c8] = *(const uint4*)(qkv + (size_t)(bs + r) * NQKV + 2048 + bc + c8);
    }
    __syncthreads();
    for (int i = tid; i < 512; i += 256) {
        int c = i >> 3, sb = (i & 7) * 8;
        alignas(16) unsigned short o[8];
#pragma unroll
        for (int jj = 0; jj < 8; ++jj) o[jj] = t[sb + jj][c];
        *(uint4*)(vT + (size_t)(bc + c) * Sq + bs + sb) = *(uint4*)o;
    }
}

// ------------------------- flash attention (causal) -------------------------
// block = (q-tile of 64, head); wave w owns q rows w*16..w*16+15
__global__ __launch_bounds__(256) void attn(
    const unsigned short* __restrict__ qb, const unsigned short* __restrict__ kb,
    const unsigned short* __restrict__ vT, unsigned short* __restrict__ ob)
{
    __shared__ __align__(16) unsigned short Qs[64 * 64];
    __shared__ __align__(16) unsigned short Ks[64 * 64];
    __shared__ __align__(16) unsigned short Vs[64 * 64];   // [d][key]
    __shared__ __align__(16) unsigned short Ps[4][16 * 64];
    int tid = threadIdx.x;
    int lane = tid & 63, wave = tid >> 6;
    int lr = lane & 15, quad = lane >> 4;
    int qt = blockIdx.x, h = blockIdx.y;
    int q0 = qt * 64;
    for (int i = tid; i < 512; i += 256) {
        int r = i >> 3, c8 = (i & 7) * 8;
        *(uint4*)(Qs + r * 64 + c8) = *(const uint4*)(qb + (size_t)(q0 + r) * Dm + h * 64 + c8);
    }
    __syncthreads();
    bf16x8 qf0 = *(const bf16x8*)(Qs + (wave * 16 + lr) * 64 + quad * 8);
    bf16x8 qf1 = *(const bf16x8*)(Qs + (wave * 16 + lr) * 64 + 32 + quad * 8);
    f32x4 zero = {0.f, 0.f, 0.f, 0.f};
    f32x4 oacc[4];
#pragma unroll
    for (int j = 0; j < 4; ++j) oacc[j] = zero;
    float mrow[4] = {-1e30f, -1e30f, -1e30f, -1e30f};
    float lrow[4] = {0.f, 0.f, 0.f, 0.f};

    for (int kt = 0; kt <= qt; ++kt) {
        for (int i = tid; i < 512; i += 256) {
            int r = i >> 3, c8 = (i & 7) * 8;
            *(uint4*)(Ks + r * 64 + c8) =
                *(const uint4*)(kb + (size_t)(kt * 64 + r) * Dm + h * 64 + c8);
            *(uint4*)(Vs + r * 64 + c8) =
                *(const uint4*)(vT + (size_t)(h * 64 + r) * Sq + kt * 64 + c8);
        }
        __syncthreads();
        f32x4 sf[4];
#pragma unroll
        for (int j = 0; j < 4; ++j) {
            bf16x8 kf0 = *(const bf16x8*)(Ks + (j * 16 + lr) * 64 + quad * 8);
            bf16x8 kf1 = *(const bf16x8*)(Ks + (j * 16 + lr) * 64 + 32 + quad * 8);
            f32x4 z = zero;
            z = __builtin_amdgcn_mfma_f32_16x16x32_bf16(qf0, kf0, z, 0, 0, 0);
            z = __builtin_amdgcn_mfma_f32_16x16x32_bf16(qf1, kf1, z, 0, 0, 0);
            sf[j] = z;
        }
        if (kt == qt) {
#pragma unroll
            for (int j = 0; j < 4; ++j)
#pragma unroll
                for (int r = 0; r < 4; ++r)
                    if (j * 16 + lr > wave * 16 + quad * 4 + r) sf[j][r] = -1e30f;
        }
#pragma unroll
        for (int r = 0; r < 4; ++r) {
            float mx = fmaxf(fmaxf(sf[0][r], sf[1][r]), fmaxf(sf[2][r], sf[3][r]));
#pragma unroll
            for (int m = 1; m < 16; m <<= 1) mx = fmaxf(mx, __shfl_xor(mx, m));
            float mnew = fmaxf(mrow[r], mx);
            float alpha = __expf(mrow[r] - mnew);
            mrow[r] = mnew;
            float rs = 0.f;
#pragma unroll
            for (int j = 0; j < 4; ++j) {
                float p = __expf(sf[j][r] - mnew);
                sf[j][r] = p; rs += p;
            }
#pragma unroll
            for (int m = 1; m < 16; m <<= 1) rs += __shfl_xor(rs, m);
            lrow[r] = lrow[r] * alpha + rs;
#pragma unroll
            for (int j = 0; j < 4; ++j) oacc[j] *= alpha;
        }
        // P (C-layout) -> LDS -> A-layout fragments
#pragma unroll
        for (int j = 0; j < 4; ++j)
#pragma unroll
            for (int r = 0; r < 4; ++r)
                Ps[wave][(quad * 4 + r) * 64 + j * 16 + lr] = f2bf(sf[j][r]);
        __syncthreads();
        bf16x8 pf0 = *(const bf16x8*)(&Ps[wave][lr * 64 + quad * 8]);
        bf16x8 pf1 = *(const bf16x8*)(&Ps[wave][lr * 64 + 32 + quad * 8]);
#pragma unroll
        for (int j = 0; j < 4; ++j) {
            bf16x8 vf0 = *(const bf16x8*)(Vs + (j * 16 + lr) * 64 + quad * 8);
            bf16x8 vf1 = *(const bf16x8*)(Vs + (j * 16 + lr) * 64 + 32 + quad * 8);
            oacc[j] = __builtin_amdgcn_mfma_f32_16x16x32_bf16(pf0, vf0, oacc[j], 0, 0, 0);
            oacc[j] = __builtin_amdgcn_mfma_f32_16x16x32_bf16(pf1, vf1, oacc[j], 0, 0, 0);
        }
        __syncthreads();   // before next tile overwrites Ks/Vs
    }
#pragma unroll
    for (int r = 0; r < 4; ++r) {
        float inv = 1.0f / lrow[r];
        int row = q0 + wave * 16 + quad * 4 + r;
#pragma unroll
        for (int j = 0; j < 4; ++j)
            ob[(size_t)row * KE2 + h * 64 + j * 16 + lr] = f2bf(oacc[j][r] * inv);
    }
}

// ------------------------------ SwiGLU --------------------------------------
__global__ __launch_bounds__(256) void swiglu(
    const unsigned short* __restrict__ gu, unsigned short* __restrict__ hb)
{
    int idx = blockIdx.x * 256 + threadIdx.x;   // over 2048*2816
    int s = idx / Fm, f = idx - s * Fm;
    float g = bf2f(gu[(size_t)s * NGU + f]);
    float u = bf2f(gu[(size_t)s * NGU + Fm + f]);
    float sig = 1.0f / (1.0f + __expf(-g));
    hb[(size_t)s * KE3 + f] = f2bf(u * g * sig);
}

// ---------------------------------------------------------------------------
extern "C" void kernel_launch(void* const* d_in, const int* in_sizes, int n_in,
                              void* d_out, int out_size, void* d_ws, size_t ws_size,
                              hipStream_t stream)
{
    const float* x    = (const float*)d_in[0];
    const float* nw1  = (const float*)d_in[1];
    const float* nw2  = (const float*)d_in[2];
    const float* cosT = (const float*)d_in[3];
    const float* sinT = (const float*)d_in[4];
    const int*   pos  = (const int*)d_in[5];
    const int   *qc = (const int*)d_in[6],  *kc = (const int*)d_in[10],
                *vc = (const int*)d_in[14], *oc = (const int*)d_in[18],
                *gc = (const int*)d_in[22], *uc = (const int*)d_in[26],
                *dc = (const int*)d_in[30];
    const float *qa = (const float*)d_in[7],  *ka = (const float*)d_in[11],
                *va = (const float*)d_in[15], *oa = (const float*)d_in[19],
                *ga = (const float*)d_in[23], *ua = (const float*)d_in[27],
                *da = (const float*)d_in[31];
    const float *qla = (const float*)d_in[8],  *kla = (const float*)d_in[12],
                *vla = (const float*)d_in[16], *ola = (const float*)d_in[20],
                *gla = (const float*)d_in[24], *ula = (const float*)d_in[28],
                *dla = (const float*)d_in[32];
    const float *qlb = (const float*)d_in[9],  *klb = (const float*)d_in[13],
                *vlb = (const float*)d_in[17], *olb = (const float*)d_in[21],
                *glb = (const float*)d_in[25], *ulb = (const float*)d_in[29],
                *dlb = (const float*)d_in[33];

    // workspace layout (bytes); Cgu overlays dead qkv/qb/kb/vT region
    char* ws = (char*)d_ws;
    unsigned short* h   = (unsigned short*)(ws + 0);          // [2048,1088] bf16
    unsigned short* W   = (unsigned short*)(ws + 4456448);    // <= [5632,1056] bf16
    unsigned short* qkv = (unsigned short*)(ws + 16351232);   // [2048,3072] bf16
    unsigned short* qbf = (unsigned short*)(ws + 28934144);   // [2048,1024] bf16
    unsigned short* kbf = (unsigned short*)(ws + 33128448);   // [2048,1024] bf16
    unsigned short* vT  = (unsigned short*)(ws + 37322752);   // [1024,2048] bf16
    unsigned short* cgu = qkv;                                // [2048,5632] bf16 (alias)
    unsigned short* obf = (unsigned short*)(ws + 41517056);   // [2048,1056] bf16
    float*          x1  = (float*)(ws + 45842432);            // [2048,1024] f32
    unsigned short* hb  = (unsigned short*)(ws + 54231040);   // [2048,2848] bf16
    float* outp = (float*)d_out;

    // ---- attention block ----
    rmsnorm_ext<<<Sq, 256, 0, stream>>>(x, nw1, h, KE1);
    lora_T<<<Sq, 256, 0, stream>>>(h, KE1, Dm, qla, 1024, 0, 0);
    lora_T<<<Sq, 256, 0, stream>>>(h, KE1, Dm, kla, 1040, 0, 0);
    lora_T<<<Sq, 256, 0, stream>>>(h, KE1, Dm, vla, 1056, 0, 0);
    dequant_ext<<<544, 256, 0, stream>>>(qc, qa, qlb, W, Dm, Dm, KE1, 1024);
    dequant_ext<<<544, 256, 0, stream>>>(kc, ka, klb, W + (size_t)1024 * KE1, Dm, Dm, KE1, 1040);
    dequant_ext<<<544, 256, 0, stream>>>(vc, va, vlb, W + (size_t)2048 * KE1, Dm, Dm, KE1, 1056);
    gemm_bf16<<<dim3(NQKV / 128, Sq / 128), 256, 0, stream>>>(h, KE1, W, KE1, KE1,
                                                              qkv, NQKV, nullptr, nullptr);
    rope_split<<<Sq * Dm / 256, 256, 0, stream>>>(qkv, cosT, sinT, pos, qbf, kbf);
    vtrans<<<dim3(Sq / 64, Dm / 64), 256, 0, stream>>>(qkv, vT);
    attn<<<dim3(Sq / 64, Hh), 256, 0, stream>>>(qbf, kbf, vT, obf);
    lora_T<<<Sq, 256, 0, stream>>>(obf, KE2, Dm, ola, 1024, 1040, 16);
    dequant_ext<<<528, 256, 0, stream>>>(oc, oa, olb, W, Dm, Dm, KE2, 1024);
    gemm_bf16<<<dim3(Dm / 128, Sq / 128), 256, 0, stream>>>(obf, KE2, W, KE2, KE2,
                                                            nullptr, Dm, x1, x);
    // ---- MLP block ----
    rmsnorm_ext<<<Sq, 256, 0, stream>>>(x1, nw2, h, KE1);
    lora_T<<<Sq, 256, 0, stream>>>(h, KE1, Dm, gla, 1024, 0, 0);
    lora_T<<<Sq, 256, 0, stream>>>(h, KE1, Dm, ula, 1040, 0, 0);
    dequant_ext<<<1452, 256, 0, stream>>>(gc, ga, glb, W, Fm, Dm, KE2, 1024);
    dequant_ext<<<1452, 256, 0, stream>>>(uc, ua, ulb, W + (size_t)Fm * KE2, Fm, Dm, KE2, 1040);
    gemm_bf16<<<dim3(NGU / 128, Sq / 128), 256, 0, stream>>>(h, KE1, W, KE2, KE2,
                                                             cgu, NGU, nullptr, nullptr);
    swiglu<<<Sq * Fm / 256, 256, 0, stream>>>(cgu, hb);
    lora_T<<<Sq, 256, 0, stream>>>(hb, KE3, Fm, dla, 2816, 2832, 16);
    dequant_ext<<<1424, 256, 0, stream>>>(dc, da, dlb, W, Dm, Fm, KE3, 2816);
    gemm_bf16<<<dim3(Dm / 128, Sq / 128), 256, 0, stream>>>(hb, KE3, W, KE3, KE3,
                                                            nullptr, Dm, outp, x1);
}

// Round 2
// 568.468 us; speedup vs baseline: 1.0571x; 1.0571x over previous
//
#include <hip/hip_runtime.h>
#include <stdint.h>

// ---------------------------------------------------------------------------
// MixedSparseSingleLayerWithGate: NF4-dequant QLoRA transformer layer, MI355X.
// R2: GEMM uses global_load_lds(16B) staging (m97 recipe); attention reworked
// (128-key tiles, padded LDS, balanced block order, alpha-scaling bugfix);
// lora_T fused per stage.
// ---------------------------------------------------------------------------

#define Sq   2048
#define Dm   1024
#define Fm   2816
#define Hh   16
#define KE1  1088   // h_ext stride / qkv GEMM K   (1024 + 16*3 + 16 pad)
#define KE2  1056   // o & gate/up GEMM K          (1024 + 16 + 16)
#define KE3  2848   // down GEMM K                 (2816 + 16 + 16)
#define NQKV 3072
#define NGU  5632

typedef short bf16x8 __attribute__((ext_vector_type(8)));
typedef float f32x4  __attribute__((ext_vector_type(4)));

__constant__ float NF4_LUT[16] = {
    -1.0f, -0.6961928009986877f, -0.5250730514526367f, -0.39491748809814453f,
    -0.28444138169288635f, -0.18477343022823334f, -0.09105003625154495f, 0.0f,
    0.07958029955625534f, 0.16093020141124725f, 0.24611230194568634f,
    0.33791524171829224f, 0.44070982933044434f, 0.5626170039176941f,
    0.7229568362236023f, 1.0f};

__device__ inline unsigned short f2bf(float f) {
    union { float f; uint32_t u; } v; v.f = f;
    uint32_t u = v.u;
    return (unsigned short)((u + 0x7FFFu + ((u >> 16) & 1u)) >> 16);
}
__device__ inline float bf2f(unsigned short h) {
    union { uint32_t u; float f; } v; v.u = ((uint32_t)h) << 16;
    return v.f;
}

// async global->LDS, 16 B per lane; LDS dest = wave-uniform base + lane*16
#define GLD16(gp, lp)                                                         \
    __builtin_amdgcn_global_load_lds(                                         \
        (__attribute__((address_space(1))) void*)(uintptr_t)(gp),             \
        (__attribute__((address_space(3))) void*)(uint32_t)(uintptr_t)(lp),   \
        16, 0, 0)

// --------------------------- rmsnorm -> bf16 ext -----------------------------
__global__ __launch_bounds__(256) void rmsnorm_ext(
    const float* __restrict__ X, const float* __restrict__ W,
    unsigned short* Hout, int ldh)
{
    int s = blockIdx.x, tid = threadIdx.x;
    const float4 v = *(const float4*)(X + (size_t)s * Dm + tid * 4);
    float ss = v.x * v.x + v.y * v.y + v.z * v.z + v.w * v.w;
#pragma unroll
    for (int m = 1; m < 64; m <<= 1) ss += __shfl_xor(ss, m);
    __shared__ float red[4];
    int lane = tid & 63, wave = tid >> 6;
    if (lane == 0) red[wave] = ss;
    __syncthreads();
    float scale = rsqrtf((red[0] + red[1] + red[2] + red[3]) * (1.0f / Dm) + 1e-10f);
    const float4 w = *(const float4*)(W + tid * 4);
    alignas(8) unsigned short o[4];
    o[0] = f2bf(v.x * scale * w.x);
    o[1] = f2bf(v.y * scale * w.y);
    o[2] = f2bf(v.z * scale * w.z);
    o[3] = f2bf(v.w * scale * w.w);
    *(ushort4*)(Hout + (size_t)s * ldh + tid * 4) = *(ushort4*)o;
    if (tid < 64) Hout[(size_t)s * ldh + Dm + tid] = 0;
}

// --------------------- T = A @ la (1..3 matrices fused) ---------------------
// writes bf16 T_m into A_ext cols [toff+16m, toff+16m+16); zeros [zoff,zoff+zn)
template<int NM>
__global__ __launch_bounds__(256) void lora_T(
    const unsigned short* Aext, int lda, int K,
    const float* __restrict__ la0, const float* __restrict__ la1,
    const float* __restrict__ la2, int toff, int zoff, int zn)
{
    int s = blockIdx.x, tid = threadIdx.x;
    const float* las[3] = {la0, la1, la2};
    float acc[16 * NM];
#pragma unroll
    for (int r = 0; r < 16 * NM; ++r) acc[r] = 0.f;
    const unsigned short* arow = Aext + (size_t)s * lda;
    for (int k = tid; k < K; k += 256) {
        float h = bf2f(arow[k]);
#pragma unroll
        for (int m = 0; m < NM; ++m) {
            const float4* lp = (const float4*)(las[m] + (size_t)k * 16);
            float4 l0 = lp[0], l1 = lp[1], l2 = lp[2], l3 = lp[3];
            float* a = acc + 16 * m;
            a[0]  += h * l0.x; a[1]  += h * l0.y; a[2]  += h * l0.z; a[3]  += h * l0.w;
            a[4]  += h * l1.x; a[5]  += h * l1.y; a[6]  += h * l1.z; a[7]  += h * l1.w;
            a[8]  += h * l2.x; a[9]  += h * l2.y; a[10] += h * l2.z; a[11] += h * l2.w;
            a[12] += h * l3.x; a[13] += h * l3.y; a[14] += h * l3.z; a[15] += h * l3.w;
        }
    }
#pragma unroll
    for (int r = 0; r < 16 * NM; ++r)
#pragma unroll
        for (int m = 1; m < 64; m <<= 1) acc[r] += __shfl_xor(acc[r], m);
    __shared__ float red[4][16 * NM];
    int lane = tid & 63, wave = tid >> 6;
    if (lane == 0)
#pragma unroll
        for (int r = 0; r < 16 * NM; ++r) red[wave][r] = acc[r];
    __syncthreads();
    unsigned short* drow = (unsigned short*)Aext + (size_t)s * lda;
    if (tid < 16 * NM)
        drow[toff + tid] = f2bf(red[0][tid] + red[1][tid] + red[2][tid] + red[3][tid]);
    if (zn > 0 && tid >= 64 && tid < 64 + zn) drow[zoff + (tid - 64)] = 0;
}

// --------------------- NF4 dequant -> bf16, K-extended ----------------------
__global__ __launch_bounds__(256) void dequant_ext(
    const int* __restrict__ codes, const float* __restrict__ absmax,
    const float* __restrict__ lb, unsigned short* __restrict__ Wout,
    int Nproj, int K, int ldw, int toff)
{
    __shared__ float lut[16];
    if (threadIdx.x < 16) lut[threadIdx.x] = NF4_LUT[threadIdx.x];
    __syncthreads();
    int idx = blockIdx.x * 256 + threadIdx.x;
    int cpr = ldw >> 3;
    int n = idx / cpr;
    if (n >= Nproj) return;
    int c8 = (idx - n * cpr) * 8;
    alignas(16) unsigned short out[8];
    if (c8 < K) {
        size_t base = (size_t)n * K + c8;
        const int4* cp = (const int4*)(codes + base);
        int4 ca = cp[0], cb = cp[1];
        float am = absmax[base >> 6];
        out[0] = f2bf(lut[ca.x] * am); out[1] = f2bf(lut[ca.y] * am);
        out[2] = f2bf(lut[ca.z] * am); out[3] = f2bf(lut[ca.w] * am);
        out[4] = f2bf(lut[cb.x] * am); out[5] = f2bf(lut[cb.y] * am);
        out[6] = f2bf(lut[cb.z] * am); out[7] = f2bf(lut[cb.w] * am);
    } else {
        int r = c8 - toff;
#pragma unroll
        for (int i = 0; i < 8; ++i) out[i] = 0;
        if (r >= 0 && r < 16) {
#pragma unroll
            for (int i = 0; i < 8; ++i) out[i] = f2bf(lb[(size_t)(r + i) * Nproj + n]);
        }
    }
    *(uint4*)(Wout + (size_t)n * ldw + c8) = *(uint4*)out;
}

// ------------------------------- bf16 GEMM ----------------------------------
// C[M,N] = A[M,K](lda) * B[N,K](ldb)^T ; 128x128 tile, BK=32, 4 waves,
// global_load_lds staging (m97 recipe).
__global__ __launch_bounds__(256) void gemm_bf16(
    const unsigned short* __restrict__ A, int lda,
    const unsigned short* __restrict__ B, int ldb, int K,
    unsigned short* __restrict__ Cb, int ldc,
    float* __restrict__ Cf, const float* __restrict__ Radd)
{
    __shared__ __align__(16) unsigned short At[128 * 32];
    __shared__ __align__(16) unsigned short Bt[128 * 32];
    int tid = threadIdx.x;
    int lane = tid & 63, wave = tid >> 6;
    int lr = lane & 15, quad = lane >> 4;
    int wm = (wave >> 1) * 64, wn = (wave & 1) * 64;
    int row0 = blockIdx.y * 128, col0 = blockIdx.x * 128;
    f32x4 acc[4][4];
    f32x4 zero = {0.f, 0.f, 0.f, 0.f};
#pragma unroll
    for (int i = 0; i < 4; ++i)
#pragma unroll
        for (int j = 0; j < 4; ++j) acc[i][j] = zero;
    const unsigned short* Ag  = A + (size_t)(row0 + (tid >> 2)) * lda + (tid & 3) * 8;
    const unsigned short* Ag2 = Ag + (size_t)64 * lda;
    const unsigned short* Bg  = B + (size_t)(col0 + (tid >> 2)) * ldb + (tid & 3) * 8;
    const unsigned short* Bg2 = Bg + (size_t)64 * ldb;
    unsigned short* lA  = At + tid * 8;
    unsigned short* lA2 = At + (tid + 256) * 8;
    unsigned short* lB  = Bt + tid * 8;
    unsigned short* lB2 = Bt + (tid + 256) * 8;
    for (int k0 = 0; k0 < K; k0 += 32) {
        __syncthreads();                       // prev-iter frag reads done
        GLD16(Ag + k0, lA);
        GLD16(Ag2 + k0, lA2);
        GLD16(Bg + k0, lB);
        GLD16(Bg2 + k0, lB2);
        __syncthreads();                       // vmcnt drained -> LDS valid
        bf16x8 af[4], bfr[4];
#pragma unroll
        for (int i = 0; i < 4; ++i)
            af[i] = *(const bf16x8*)(At + (wm + i * 16 + lr) * 32 + quad * 8);
#pragma unroll
        for (int j = 0; j < 4; ++j)
            bfr[j] = *(const bf16x8*)(Bt + (wn + j * 16 + lr) * 32 + quad * 8);
#pragma unroll
        for (int i = 0; i < 4; ++i)
#pragma unroll
            for (int j = 0; j < 4; ++j)
                acc[i][j] = __builtin_amdgcn_mfma_f32_16x16x32_bf16(af[i], bfr[j], acc[i][j], 0, 0, 0);
    }
#pragma unroll
    for (int i = 0; i < 4; ++i) {
        int rowb = row0 + wm + i * 16 + quad * 4;
#pragma unroll
        for (int j = 0; j < 4; ++j) {
            int col = col0 + wn + j * 16 + lr;
#pragma unroll
            for (int r = 0; r < 4; ++r) {
                float v = acc[i][j][r];
                size_t o = (size_t)(rowb + r) * ldc + col;
                if (Cb) Cb[o] = f2bf(v);
                else    Cf[o] = v + Radd[o];
            }
        }
    }
}

// ----------------------- rope + split q/k (scaled q) ------------------------
__global__ __launch_bounds__(256) void rope_split(
    const unsigned short* __restrict__ qkv,
    const float* __restrict__ cosT, const float* __restrict__ sinT,
    const int* __restrict__ pos,
    unsigned short* __restrict__ qb, unsigned short* __restrict__ kb)
{
    int idx = blockIdx.x * 256 + threadIdx.x;   // over 2048*1024
    int s = idx >> 10, col = idx & 1023, d = col & 63;
    int p = pos[s];
    float c = cosT[p * 64 + d], sn = sinT[p * 64 + d];
    int partner = (d < 32) ? (col + 32) : (col - 32);
    float sgn = (d < 32) ? -1.f : 1.f;
    const unsigned short* row = qkv + (size_t)s * NQKV;
    float q = bf2f(row[col]), q2 = bf2f(row[partner]);
    float k = bf2f(row[Dm + col]), k2 = bf2f(row[Dm + partner]);
    qb[idx] = f2bf((q * c + sgn * q2 * sn) * 0.125f);   // 1/sqrt(DH) folded in
    kb[idx] = f2bf(k * c + sgn * k2 * sn);
}

// -------------------- transpose V slice: vT[d, s] ---------------------------
__global__ __launch_bounds__(256) void vtrans(
    const unsigned short* __restrict__ qkv, unsigned short* __restrict__ vT)
{
    __shared__ __align__(16) unsigned short t[64][80];
    int bs = blockIdx.x * 64, bc = blockIdx.y * 64;
    int tid = threadIdx.x;
    for (int i = tid; i < 512; i += 256) {
        int r = i >> 3, c8 = (i & 7) * 8;
        *(uint4*)&t[r][c8] = *(const uint4*)(qkv + (size_t)(bs + r) * NQKV + 2048 + bc + c8);
    }
    __syncthreads();
    for (int i = tid; i < 512; i += 256) {
        int c = i >> 3, sb = (i & 7) * 8;
        alignas(16) unsigned short o[8];
#pragma unroll
        for (int jj = 0; jj < 8; ++jj) o[jj] = t[sb + jj][c];
        *(uint4*)(vT + (size_t)(bc + c) * Sq + bs + sb) = *(uint4*)o;
    }
}

// ------------------------- flash attention (causal) -------------------------
// 1-D grid of 512 blocks: idx -> (qt, head) with heavy qt first and
// pair-sum-constant mapping so co-resident blocks balance.
// Per block: 64 q rows (wave owns 16), 128-key inner tiles, padded LDS.
__global__ __launch_bounds__(256) void attn(
    const unsigned short* __restrict__ qb, const unsigned short* __restrict__ kb,
    const unsigned short* __restrict__ vT, unsigned short* __restrict__ ob)
{
    __shared__ __align__(16) unsigned short Ks[128 * 72];     // [key][d] +8 pad
    __shared__ __align__(16) unsigned short Vs[64 * 136];     // [d][key] +8 pad
    __shared__ __align__(16) unsigned short Ps[4][16 * 136];  // per-wave P
    int tid = threadIdx.x;
    int lane = tid & 63, wave = tid >> 6;
    int lr = lane & 15, quad = lane >> 4;
    int idx = blockIdx.x;
    int t = idx >> 4;
    int qt = (idx < 256) ? (31 - t) : (t - 16);
    int h = idx & 15;
    int q0 = qt * 64;
    const unsigned short* qp = qb + (size_t)(q0 + wave * 16 + lr) * Dm + h * 64 + quad * 8;
    bf16x8 qf0 = *(const bf16x8*)qp;
    bf16x8 qf1 = *(const bf16x8*)(qp + 32);
    f32x4 zero = {0.f, 0.f, 0.f, 0.f};
    f32x4 oacc[4];
#pragma unroll
    for (int j = 0; j < 4; ++j) oacc[j] = zero;
    float mrow[4] = {-1e30f, -1e30f, -1e30f, -1e30f};
    float lrow[4] = {0.f, 0.f, 0.f, 0.f};
    int ntile = (q0 + 64 + 127) >> 7;

    for (int kt = 0; kt < ntile; ++kt) {
        int k0 = kt << 7;
        for (int i = tid; i < 1024; i += 256) {
            int r = i >> 3, c8 = (i & 7) * 8;
            *(uint4*)(Ks + r * 72 + c8) =
                *(const uint4*)(kb + (size_t)(k0 + r) * Dm + h * 64 + c8);
        }
        for (int i = tid; i < 1024; i += 256) {
            int r = i >> 4, c8 = (i & 15) * 8;
            *(uint4*)(Vs + r * 136 + c8) =
                *(const uint4*)(vT + (size_t)(h * 64 + r) * Sq + k0 + c8);
        }
        __syncthreads();
        f32x4 sf[8];
#pragma unroll
        for (int jj = 0; jj < 8; ++jj) {
            bf16x8 kf0 = *(const bf16x8*)(Ks + (jj * 16 + lr) * 72 + quad * 8);
            bf16x8 kf1 = *(const bf16x8*)(Ks + (jj * 16 + lr) * 72 + 32 + quad * 8);
            f32x4 z = zero;
            z = __builtin_amdgcn_mfma_f32_16x16x32_bf16(qf0, kf0, z, 0, 0, 0);
            z = __builtin_amdgcn_mfma_f32_16x16x32_bf16(qf1, kf1, z, 0, 0, 0);
            sf[jj] = z;
        }
        if (kt == ntile - 1) {
#pragma unroll
            for (int jj = 0; jj < 8; ++jj)
#pragma unroll
                for (int r = 0; r < 4; ++r)
                    if (k0 + jj * 16 + lr > q0 + wave * 16 + quad * 4 + r)
                        sf[jj][r] = -1e30f;
        }
#pragma unroll
        for (int r = 0; r < 4; ++r) {
            float mx = sf[0][r];
#pragma unroll
            for (int jj = 1; jj < 8; ++jj) mx = fmaxf(mx, sf[jj][r]);
#pragma unroll
            for (int m = 1; m < 16; m <<= 1) mx = fmaxf(mx, __shfl_xor(mx, m));
            float mnew = fmaxf(mrow[r], mx);
            float alpha = __expf(mrow[r] - mnew);
            mrow[r] = mnew;
            float rs = 0.f;
#pragma unroll
            for (int jj = 0; jj < 8; ++jj) {
                float p = __expf(sf[jj][r] - mnew);
                sf[jj][r] = p; rs += p;
            }
#pragma unroll
            for (int m = 1; m < 16; m <<= 1) rs += __shfl_xor(rs, m);
            lrow[r] = lrow[r] * alpha + rs;
#pragma unroll
            for (int j = 0; j < 4; ++j) oacc[j][r] *= alpha;   // per-row alpha (bugfix)
        }
        // P (C-layout) -> per-wave LDS -> A-layout frags (no barrier: wave-private)
#pragma unroll
        for (int jj = 0; jj < 8; ++jj)
#pragma unroll
            for (int r = 0; r < 4; ++r)
                Ps[wave][(quad * 4 + r) * 136 + jj * 16 + lr] = f2bf(sf[jj][r]);
        bf16x8 pf[4];
#pragma unroll
        for (int kk = 0; kk < 4; ++kk)
            pf[kk] = *(const bf16x8*)(&Ps[wave][lr * 136 + kk * 32 + quad * 8]);
#pragma unroll
        for (int j = 0; j < 4; ++j) {
#pragma unroll
            for (int kk = 0; kk < 4; ++kk) {
                bf16x8 vf = *(const bf16x8*)(Vs + (j * 16 + lr) * 136 + kk * 32 + quad * 8);
                oacc[j] = __builtin_amdgcn_mfma_f32_16x16x32_bf16(pf[kk], vf, oacc[j], 0, 0, 0);
            }
        }
        __syncthreads();   // before next tile overwrites Ks/Vs
    }
#pragma unroll
    for (int r = 0; r < 4; ++r) {
        float inv = 1.0f / lrow[r];
        int row = q0 + wave * 16 + quad * 4 + r;
#pragma unroll
        for (int j = 0; j < 4; ++j)
            ob[(size_t)row * KE2 + h * 64 + j * 16 + lr] = f2bf(oacc[j][r] * inv);
    }
}

// ------------------------------ SwiGLU --------------------------------------
__global__ __launch_bounds__(256) void swiglu(
    const unsigned short* __restrict__ gu, unsigned short* __restrict__ hb)
{
    int idx = blockIdx.x * 256 + threadIdx.x;   // over 2048*2816
    int s = idx / Fm, f = idx - s * Fm;
    float g = bf2f(gu[(size_t)s * NGU + f]);
    float u = bf2f(gu[(size_t)s * NGU + Fm + f]);
    float sig = 1.0f / (1.0f + __expf(-g));
    hb[(size_t)s * KE3 + f] = f2bf(u * g * sig);
}

// ---------------------------------------------------------------------------
extern "C" void kernel_launch(void* const* d_in, const int* in_sizes, int n_in,
                              void* d_out, int out_size, void* d_ws, size_t ws_size,
                              hipStream_t stream)
{
    const float* x    = (const float*)d_in[0];
    const float* nw1  = (const float*)d_in[1];
    const float* nw2  = (const float*)d_in[2];
    const float* cosT = (const float*)d_in[3];
    const float* sinT = (const float*)d_in[4];
    const int*   pos  = (const int*)d_in[5];
    const int   *qc = (const int*)d_in[6],  *kc = (const int*)d_in[10],
                *vc = (const int*)d_in[14], *oc = (const int*)d_in[18],
                *gc = (const int*)d_in[22], *uc = (const int*)d_in[26],
                *dc = (const int*)d_in[30];
    const float *qa = (const float*)d_in[7],  *ka = (const float*)d_in[11],
                *va = (const float*)d_in[15], *oa = (const float*)d_in[19],
                *ga = (const float*)d_in[23], *ua = (const float*)d_in[27],
                *da = (const float*)d_in[31];
    const float *qla = (const float*)d_in[8],  *kla = (const float*)d_in[12],
                *vla = (const float*)d_in[16], *ola = (const float*)d_in[20],
                *gla = (const float*)d_in[24], *ula = (const float*)d_in[28],
                *dla = (const float*)d_in[32];
    const float *qlb = (const float*)d_in[9],  *klb = (const float*)d_in[13],
                *vlb = (const float*)d_in[17], *olb = (const float*)d_in[21],
                *glb = (const float*)d_in[25], *ulb = (const float*)d_in[29],
                *dlb = (const float*)d_in[33];

    char* ws = (char*)d_ws;
    unsigned short* h   = (unsigned short*)(ws + 0);          // [2048,1088] bf16
    unsigned short* W   = (unsigned short*)(ws + 4456448);    // <= [5632,1056] bf16
    unsigned short* qkv = (unsigned short*)(ws + 16351232);   // [2048,3072] bf16
    unsigned short* qbf = (unsigned short*)(ws + 28934144);   // [2048,1024] bf16
    unsigned short* kbf = (unsigned short*)(ws + 33128448);   // [2048,1024] bf16
    unsigned short* vT  = (unsigned short*)(ws + 37322752);   // [1024,2048] bf16
    unsigned short* cgu = qkv;                                // [2048,5632] bf16 (alias)
    unsigned short* obf = (unsigned short*)(ws + 41517056);   // [2048,1056] bf16
    float*          x1  = (float*)(ws + 45842432);            // [2048,1024] f32
    unsigned short* hb  = (unsigned short*)(ws + 54231040);   // [2048,2848] bf16
    float* outp = (float*)d_out;

    // ---- attention block ----
    rmsnorm_ext<<<Sq, 256, 0, stream>>>(x, nw1, h, KE1);
    lora_T<3><<<Sq, 256, 0, stream>>>(h, KE1, Dm, qla, kla, vla, 1024, 0, 0);
    dequant_ext<<<544, 256, 0, stream>>>(qc, qa, qlb, W, Dm, Dm, KE1, 1024);
    dequant_ext<<<544, 256, 0, stream>>>(kc, ka, klb, W + (size_t)1024 * KE1, Dm, Dm, KE1, 1040);
    dequant_ext<<<544, 256, 0, stream>>>(vc, va, vlb, W + (size_t)2048 * KE1, Dm, Dm, KE1, 1056);
    gemm_bf16<<<dim3(NQKV / 128, Sq / 128), 256, 0, stream>>>(h, KE1, W, KE1, KE1,
                                                              qkv, NQKV, nullptr, nullptr);
    rope_split<<<Sq * Dm / 256, 256, 0, stream>>>(qkv, cosT, sinT, pos, qbf, kbf);
    vtrans<<<dim3(Sq / 64, Dm / 64), 256, 0, stream>>>(qkv, vT);
    attn<<<512, 256, 0, stream>>>(qbf, kbf, vT, obf);
    lora_T<1><<<Sq, 256, 0, stream>>>(obf, KE2, Dm, ola, nullptr, nullptr, 1024, 1040, 16);
    dequant_ext<<<528, 256, 0, stream>>>(oc, oa, olb, W, Dm, Dm, KE2, 1024);
    gemm_bf16<<<dim3(Dm / 128, Sq / 128), 256, 0, stream>>>(obf, KE2, W, KE2, KE2,
                                                            nullptr, Dm, x1, x);
    // ---- MLP block ----
    rmsnorm_ext<<<Sq, 256, 0, stream>>>(x1, nw2, h, KE1);
    lora_T<2><<<Sq, 256, 0, stream>>>(h, KE1, Dm, gla, ula, nullptr, 1024, 0, 0);
    dequant_ext<<<1452, 256, 0, stream>>>(gc, ga, glb, W, Fm, Dm, KE2, 1024);
    dequant_ext<<<1452, 256, 0, stream>>>(uc, ua, ulb, W + (size_t)Fm * KE2, Fm, Dm, KE2, 1040);
    gemm_bf16<<<dim3(NGU / 128, Sq / 128), 256, 0, stream>>>(h, KE1, W, KE2, KE2,
                                                             cgu, NGU, nullptr, nullptr);
    swiglu<<<Sq * Fm / 256, 256, 0, stream>>>(cgu, hb);
    lora_T<1><<<Sq, 256, 0, stream>>>(hb, KE3, Fm, dla, nullptr, nullptr, 2816, 2832, 16);
    dequant_ext<<<1424, 256, 0, stream>>>(dc, da, dlb, W, Dm, Fm, KE3, 2816);
    gemm_bf16<<<dim3(Dm / 128, Sq / 128), 256, 0, stream>>>(hb, KE3, W, KE3, KE3,
                                                            nullptr, Dm, outp, x1);
}

// Round 4
// 559.424 us; speedup vs baseline: 1.0742x; 1.0162x over previous
//
#include <hip/hip_runtime.h>
#include <stdint.h>

// ---------------------------------------------------------------------------
// MixedSparseSingleLayerWithGate: NF4-dequant QLoRA transformer layer, MI355X.
// R4 = R3 with compile fix (gemm64 final call was missing ldc).
// GEMMs use 2-stage LDS double-buffer; BN=64 variant for o/down; SwiGLU fused
// into gate/up GEMM epilogue; dequants fused; rope+vtrans fused.
// ---------------------------------------------------------------------------

#define Sq   2048
#define Dm   1024
#define Fm   2816
#define Hh   16
#define KE1  1088   // h_ext stride / qkv GEMM K   (1024 + 16*3 + 16 pad)
#define KE2  1056   // o & gate/up GEMM K          (1024 + 16 + 16)
#define KE3  2848   // down GEMM K                 (2816 + 16 + 16)
#define NQKV 3072
#define NGU  5632

typedef short bf16x8 __attribute__((ext_vector_type(8)));
typedef float f32x4  __attribute__((ext_vector_type(4)));

__constant__ float NF4_LUT[16] = {
    -1.0f, -0.6961928009986877f, -0.5250730514526367f, -0.39491748809814453f,
    -0.28444138169288635f, -0.18477343022823334f, -0.09105003625154495f, 0.0f,
    0.07958029955625534f, 0.16093020141124725f, 0.24611230194568634f,
    0.33791524171829224f, 0.44070982933044434f, 0.5626170039176941f,
    0.7229568362236023f, 1.0f};

__device__ inline unsigned short f2bf(float f) {
    union { float f; uint32_t u; } v; v.f = f;
    uint32_t u = v.u;
    return (unsigned short)((u + 0x7FFFu + ((u >> 16) & 1u)) >> 16);
}
__device__ inline float bf2f(unsigned short h) {
    union { uint32_t u; float f; } v; v.u = ((uint32_t)h) << 16;
    return v.f;
}

// async global->LDS, 16 B per lane; LDS dest = wave-uniform base + lane*16
#define GLD16(gp, lp)                                                         \
    __builtin_amdgcn_global_load_lds(                                         \
        (__attribute__((address_space(1))) void*)(uintptr_t)(gp),             \
        (__attribute__((address_space(3))) void*)(uint32_t)(uintptr_t)(lp),   \
        16, 0, 0)

// --------------------------- rmsnorm -> bf16 ext -----------------------------
__global__ __launch_bounds__(256) void rmsnorm_ext(
    const float* __restrict__ X, const float* __restrict__ W,
    unsigned short* Hout, int ldh)
{
    int s = blockIdx.x, tid = threadIdx.x;
    const float4 v = *(const float4*)(X + (size_t)s * Dm + tid * 4);
    float ss = v.x * v.x + v.y * v.y + v.z * v.z + v.w * v.w;
#pragma unroll
    for (int m = 1; m < 64; m <<= 1) ss += __shfl_xor(ss, m);
    __shared__ float red[4];
    int lane = tid & 63, wave = tid >> 6;
    if (lane == 0) red[wave] = ss;
    __syncthreads();
    float scale = rsqrtf((red[0] + red[1] + red[2] + red[3]) * (1.0f / Dm) + 1e-10f);
    const float4 w = *(const float4*)(W + tid * 4);
    alignas(8) unsigned short o[4];
    o[0] = f2bf(v.x * scale * w.x);
    o[1] = f2bf(v.y * scale * w.y);
    o[2] = f2bf(v.z * scale * w.z);
    o[3] = f2bf(v.w * scale * w.w);
    *(ushort4*)(Hout + (size_t)s * ldh + tid * 4) = *(ushort4*)o;
    if (tid < 64) Hout[(size_t)s * ldh + Dm + tid] = 0;
}

// --------------------- T = A @ la (1..3 matrices fused) ---------------------
template<int NM>
__global__ __launch_bounds__(256) void lora_T(
    const unsigned short* Aext, int lda, int K,
    const float* __restrict__ la0, const float* __restrict__ la1,
    const float* __restrict__ la2, int toff, int zoff, int zn)
{
    int s = blockIdx.x, tid = threadIdx.x;
    const float* las[3] = {la0, la1, la2};
    float acc[16 * NM];
#pragma unroll
    for (int r = 0; r < 16 * NM; ++r) acc[r] = 0.f;
    const unsigned short* arow = Aext + (size_t)s * lda;
    for (int k4 = tid * 4; k4 < K; k4 += 1024) {
        ushort4 hv = *(const ushort4*)(arow + k4);
        float hf[4] = {bf2f(hv.x), bf2f(hv.y), bf2f(hv.z), bf2f(hv.w)};
#pragma unroll
        for (int m = 0; m < NM; ++m) {
            float* a = acc + 16 * m;
#pragma unroll
            for (int e = 0; e < 4; ++e) {
                const float4* lp = (const float4*)(las[m] + (size_t)(k4 + e) * 16);
                float4 l0 = lp[0], l1 = lp[1], l2 = lp[2], l3 = lp[3];
                float h = hf[e];
                a[0]  += h * l0.x; a[1]  += h * l0.y; a[2]  += h * l0.z; a[3]  += h * l0.w;
                a[4]  += h * l1.x; a[5]  += h * l1.y; a[6]  += h * l1.z; a[7]  += h * l1.w;
                a[8]  += h * l2.x; a[9]  += h * l2.y; a[10] += h * l2.z; a[11] += h * l2.w;
                a[12] += h * l3.x; a[13] += h * l3.y; a[14] += h * l3.z; a[15] += h * l3.w;
            }
        }
    }
#pragma unroll
    for (int r = 0; r < 16 * NM; ++r)
#pragma unroll
        for (int m = 1; m < 64; m <<= 1) acc[r] += __shfl_xor(acc[r], m);
    __shared__ float red[4][16 * NM];
    int lane = tid & 63, wave = tid >> 6;
    if (lane == 0)
#pragma unroll
        for (int r = 0; r < 16 * NM; ++r) red[wave][r] = acc[r];
    __syncthreads();
    unsigned short* drow = (unsigned short*)Aext + (size_t)s * lda;
    if (tid < 16 * NM)
        drow[toff + tid] = f2bf(red[0][tid] + red[1][tid] + red[2][tid] + red[3][tid]);
    if (zn > 0 && tid >= 64 && tid < 64 + zn) drow[zoff + (tid - 64)] = 0;
}

// ---------------- NF4 dequant helpers (bf16, K-extended rows) ---------------
__device__ inline void dq_row8(const float* lut, const int* cod, const float* am,
                               const float* lb, int nr, int c8, int K, int Nlb,
                               int toff, unsigned short* out)
{
    if (c8 < K) {
        size_t base = (size_t)nr * K + c8;
        const int4* cp = (const int4*)(cod + base);
        int4 ca = cp[0], cb = cp[1];
        float a = am[base >> 6];
        out[0] = f2bf(lut[ca.x] * a); out[1] = f2bf(lut[ca.y] * a);
        out[2] = f2bf(lut[ca.z] * a); out[3] = f2bf(lut[ca.w] * a);
        out[4] = f2bf(lut[cb.x] * a); out[5] = f2bf(lut[cb.y] * a);
        out[6] = f2bf(lut[cb.z] * a); out[7] = f2bf(lut[cb.w] * a);
    } else {
        int r = c8 - toff;
#pragma unroll
        for (int i = 0; i < 8; ++i) out[i] = 0;
        if (r >= 0 && r < 16) {
#pragma unroll
            for (int i = 0; i < 8; ++i) out[i] = f2bf(lb[(size_t)(r + i) * Nlb + nr]);
        }
    }
}

// q/k/v fused: W rows [0,1024)=q, [1024,2048)=k, [2048,3072)=v ; ldw=KE1
__global__ __launch_bounds__(256) void dequant_qkv(
    const int* __restrict__ qc, const int* __restrict__ kc, const int* __restrict__ vc,
    const float* __restrict__ qa, const float* __restrict__ ka, const float* __restrict__ va,
    const float* __restrict__ qlb, const float* __restrict__ klb, const float* __restrict__ vlb,
    unsigned short* __restrict__ Wout)
{
    __shared__ float lut[16];
    if (threadIdx.x < 16) lut[threadIdx.x] = NF4_LUT[threadIdx.x];
    __syncthreads();
    int idx = blockIdx.x * 256 + threadIdx.x;        // 3072*136
    int n = idx / 136;
    int c8 = (idx - n * 136) * 8;
    int seg = n >> 10, nr = n & 1023;
    const int* cod   = (seg == 0) ? qc : (seg == 1) ? kc : vc;
    const float* am  = (seg == 0) ? qa : (seg == 1) ? ka : va;
    const float* lb  = (seg == 0) ? qlb : (seg == 1) ? klb : vlb;
    int toff = 1024 + (seg << 4);
    alignas(16) unsigned short out[8];
    dq_row8(lut, cod, am, lb, nr, c8, 1024, 1024, toff, out);
    *(uint4*)(Wout + (size_t)n * KE1 + c8) = *(uint4*)out;
}

// gate/up fused + interleaved: W row 2m = gate m (toff 1024), 2m+1 = up m (1040)
__global__ __launch_bounds__(256) void dequant_gu(
    const int* __restrict__ gc, const int* __restrict__ uc,
    const float* __restrict__ ga, const float* __restrict__ ua,
    const float* __restrict__ glb, const float* __restrict__ ulb,
    unsigned short* __restrict__ Wout)
{
    __shared__ float lut[16];
    if (threadIdx.x < 16) lut[threadIdx.x] = NF4_LUT[threadIdx.x];
    __syncthreads();
    int idx = blockIdx.x * 256 + threadIdx.x;        // 5632*132
    int n = idx / 132;
    int c8 = (idx - n * 132) * 8;
    int m = n >> 1, mat = n & 1;
    const int* cod  = mat ? uc : gc;
    const float* am = mat ? ua : ga;
    const float* lb = mat ? ulb : glb;
    int toff = 1024 + (mat << 4);
    alignas(16) unsigned short out[8];
    dq_row8(lut, cod, am, lb, m, c8, 1024, Fm, toff, out);
    *(uint4*)(Wout + (size_t)n * KE2 + c8) = *(uint4*)out;
}

// generic (o-proj, down)
__global__ __launch_bounds__(256) void dequant_ext(
    const int* __restrict__ codes, const float* __restrict__ absmax,
    const float* __restrict__ lb, unsigned short* __restrict__ Wout,
    int Nproj, int K, int ldw, int toff)
{
    __shared__ float lut[16];
    if (threadIdx.x < 16) lut[threadIdx.x] = NF4_LUT[threadIdx.x];
    __syncthreads();
    int idx = blockIdx.x * 256 + threadIdx.x;
    int cpr = ldw >> 3;
    int n = idx / cpr;
    if (n >= Nproj) return;
    int c8 = (idx - n * cpr) * 8;
    alignas(16) unsigned short out[8];
    dq_row8(lut, codes, absmax, lb, n, c8, K, Nproj, toff, out);
    *(uint4*)(Wout + (size_t)n * ldw + c8) = *(uint4*)out;
}

// ------------------- GEMM 128x128, dbuf, bf16-out (qkv) ---------------------
__global__ __launch_bounds__(256) void gemm128(
    const unsigned short* __restrict__ A, int lda,
    const unsigned short* __restrict__ B, int ldb, int K,
    unsigned short* __restrict__ Cb, int ldc)
{
    __shared__ __align__(16) unsigned short At[2][128 * 32];
    __shared__ __align__(16) unsigned short Bt[2][128 * 32];
    int tid = threadIdx.x;
    int lane = tid & 63, wave = tid >> 6;
    int lr = lane & 15, quad = lane >> 4;
    int wm = (wave >> 1) * 64, wn = (wave & 1) * 64;
    int row0 = blockIdx.y * 128, col0 = blockIdx.x * 128;
    f32x4 acc[4][4];
    f32x4 zero = {0.f, 0.f, 0.f, 0.f};
#pragma unroll
    for (int i = 0; i < 4; ++i)
#pragma unroll
        for (int j = 0; j < 4; ++j) acc[i][j] = zero;
    const unsigned short* Ag  = A + (size_t)(row0 + (tid >> 2)) * lda + (tid & 3) * 8;
    const unsigned short* Ag2 = Ag + (size_t)64 * lda;
    const unsigned short* Bg  = B + (size_t)(col0 + (tid >> 2)) * ldb + (tid & 3) * 8;
    const unsigned short* Bg2 = Bg + (size_t)64 * ldb;
    int l0 = tid * 8, l1 = (tid + 256) * 8;
    GLD16(Ag, At[0] + l0); GLD16(Ag2, At[0] + l1);
    GLD16(Bg, Bt[0] + l0); GLD16(Bg2, Bt[0] + l1);
    int nIter = K >> 5;
    for (int it = 0; it < nIter; ++it) {
        int cur = it & 1;
        __syncthreads();                       // drains tile-it loads, syncs bufs
        if (it + 1 < nIter) {                  // prefetch overlaps compute below
            int k = (it + 1) << 5, nx = cur ^ 1;
            GLD16(Ag + k, At[nx] + l0); GLD16(Ag2 + k, At[nx] + l1);
            GLD16(Bg + k, Bt[nx] + l0); GLD16(Bg2 + k, Bt[nx] + l1);
        }
        bf16x8 af[4], bfr[4];
#pragma unroll
        for (int i = 0; i < 4; ++i)
            af[i] = *(const bf16x8*)(At[cur] + (wm + i * 16 + lr) * 32 + quad * 8);
#pragma unroll
        for (int j = 0; j < 4; ++j)
            bfr[j] = *(const bf16x8*)(Bt[cur] + (wn + j * 16 + lr) * 32 + quad * 8);
#pragma unroll
        for (int i = 0; i < 4; ++i)
#pragma unroll
            for (int j = 0; j < 4; ++j)
                acc[i][j] = __builtin_amdgcn_mfma_f32_16x16x32_bf16(af[i], bfr[j], acc[i][j], 0, 0, 0);
    }
#pragma unroll
    for (int i = 0; i < 4; ++i) {
        int rowb = row0 + wm + i * 16 + quad * 4;
#pragma unroll
        for (int j = 0; j < 4; ++j) {
            int col = col0 + wn + j * 16 + lr;
#pragma unroll
            for (int r = 0; r < 4; ++r)
                Cb[(size_t)(rowb + r) * ldc + col] = f2bf(acc[i][j][r]);
        }
    }
}

// ---------------- GEMM 128x128, dbuf, SwiGLU epilogue (gate/up) -------------
// B rows interleaved g/u; out hb[row, col>>1] = u * silu(g), ld KE3
__global__ __launch_bounds__(256) void gemm_gu(
    const unsigned short* __restrict__ A, int lda,
    const unsigned short* __restrict__ B, int ldb, int K,
    unsigned short* __restrict__ Hb)
{
    __shared__ __align__(16) unsigned short At[2][128 * 32];
    __shared__ __align__(16) unsigned short Bt[2][128 * 32];
    int tid = threadIdx.x;
    int lane = tid & 63, wave = tid >> 6;
    int lr = lane & 15, quad = lane >> 4;
    int wm = (wave >> 1) * 64, wn = (wave & 1) * 64;
    int row0 = blockIdx.y * 128, col0 = blockIdx.x * 128;
    f32x4 acc[4][4];
    f32x4 zero = {0.f, 0.f, 0.f, 0.f};
#pragma unroll
    for (int i = 0; i < 4; ++i)
#pragma unroll
        for (int j = 0; j < 4; ++j) acc[i][j] = zero;
    const unsigned short* Ag  = A + (size_t)(row0 + (tid >> 2)) * lda + (tid & 3) * 8;
    const unsigned short* Ag2 = Ag + (size_t)64 * lda;
    const unsigned short* Bg  = B + (size_t)(col0 + (tid >> 2)) * ldb + (tid & 3) * 8;
    const unsigned short* Bg2 = Bg + (size_t)64 * ldb;
    int l0 = tid * 8, l1 = (tid + 256) * 8;
    GLD16(Ag, At[0] + l0); GLD16(Ag2, At[0] + l1);
    GLD16(Bg, Bt[0] + l0); GLD16(Bg2, Bt[0] + l1);
    int nIter = K >> 5;
    for (int it = 0; it < nIter; ++it) {
        int cur = it & 1;
        __syncthreads();
        if (it + 1 < nIter) {
            int k = (it + 1) << 5, nx = cur ^ 1;
            GLD16(Ag + k, At[nx] + l0); GLD16(Ag2 + k, At[nx] + l1);
            GLD16(Bg + k, Bt[nx] + l0); GLD16(Bg2 + k, Bt[nx] + l1);
        }
        bf16x8 af[4], bfr[4];
#pragma unroll
        for (int i = 0; i < 4; ++i)
            af[i] = *(const bf16x8*)(At[cur] + (wm + i * 16 + lr) * 32 + quad * 8);
#pragma unroll
        for (int j = 0; j < 4; ++j)
            bfr[j] = *(const bf16x8*)(Bt[cur] + (wn + j * 16 + lr) * 32 + quad * 8);
#pragma unroll
        for (int i = 0; i < 4; ++i)
#pragma unroll
            for (int j = 0; j < 4; ++j)
                acc[i][j] = __builtin_amdgcn_mfma_f32_16x16x32_bf16(af[i], bfr[j], acc[i][j], 0, 0, 0);
    }
#pragma unroll
    for (int i = 0; i < 4; ++i) {
        int rowb = row0 + wm + i * 16 + quad * 4;
#pragma unroll
        for (int j = 0; j < 4; ++j) {
            int col = col0 + wn + j * 16 + lr;     // even=gate, odd=up
#pragma unroll
            for (int r = 0; r < 4; ++r) {
                float own = acc[i][j][r];
                float oth = __shfl_xor(own, 1);
                if (!(lr & 1)) {                   // even lane: own=g, oth=u
                    float sig = 1.0f / (1.0f + __expf(-own));
                    Hb[(size_t)(rowb + r) * KE3 + (col >> 1)] = f2bf(oth * own * sig);
                }
            }
        }
    }
}

// ------------- GEMM 128x64, dbuf, f32 + residual out (o, down) --------------
__global__ __launch_bounds__(256) void gemm64(
    const unsigned short* __restrict__ A, int lda,
    const unsigned short* __restrict__ B, int ldb, int K,
    float* __restrict__ Cf, int ldc, const float* __restrict__ Radd)
{
    __shared__ __align__(16) unsigned short At[2][128 * 32];
    __shared__ __align__(16) unsigned short Bt[2][64 * 32];
    int tid = threadIdx.x;
    int lane = tid & 63, wave = tid >> 6;
    int lr = lane & 15, quad = lane >> 4;
    int wm = wave * 32;
    int row0 = blockIdx.y * 128, col0 = blockIdx.x * 64;
    f32x4 acc[2][4];
    f32x4 zero = {0.f, 0.f, 0.f, 0.f};
#pragma unroll
    for (int i = 0; i < 2; ++i)
#pragma unroll
        for (int j = 0; j < 4; ++j) acc[i][j] = zero;
    const unsigned short* Ag  = A + (size_t)(row0 + (tid >> 2)) * lda + (tid & 3) * 8;
    const unsigned short* Ag2 = Ag + (size_t)64 * lda;
    const unsigned short* Bg  = B + (size_t)(col0 + (tid >> 2)) * ldb + (tid & 3) * 8;
    int l0 = tid * 8, l1 = (tid + 256) * 8;
    GLD16(Ag, At[0] + l0); GLD16(Ag2, At[0] + l1);
    GLD16(Bg, Bt[0] + l0);
    int nIter = K >> 5;
    for (int it = 0; it < nIter; ++it) {
        int cur = it & 1;
        __syncthreads();
        if (it + 1 < nIter) {
            int k = (it + 1) << 5, nx = cur ^ 1;
            GLD16(Ag + k, At[nx] + l0); GLD16(Ag2 + k, At[nx] + l1);
            GLD16(Bg + k, Bt[nx] + l0);
        }
        bf16x8 af[2], bfr[4];
#pragma unroll
        for (int i = 0; i < 2; ++i)
            af[i] = *(const bf16x8*)(At[cur] + (wm + i * 16 + lr) * 32 + quad * 8);
#pragma unroll
        for (int j = 0; j < 4; ++j)
            bfr[j] = *(const bf16x8*)(Bt[cur] + (j * 16 + lr) * 32 + quad * 8);
#pragma unroll
        for (int i = 0; i < 2; ++i)
#pragma unroll
            for (int j = 0; j < 4; ++j)
                acc[i][j] = __builtin_amdgcn_mfma_f32_16x16x32_bf16(af[i], bfr[j], acc[i][j], 0, 0, 0);
    }
#pragma unroll
    for (int i = 0; i < 2; ++i) {
        int rowb = row0 + wm + i * 16 + quad * 4;
#pragma unroll
        for (int j = 0; j < 4; ++j) {
            int col = col0 + j * 16 + lr;
#pragma unroll
            for (int r = 0; r < 4; ++r) {
                size_t o = (size_t)(rowb + r) * ldc + col;
                Cf[o] = acc[i][j][r] + Radd[o];
            }
        }
    }
}

// ---------------- fused rope(q,k) + V-transpose ----------------------------
__global__ __launch_bounds__(256) void rope_vtrans(
    const unsigned short* __restrict__ qkv,
    const float* __restrict__ cosT, const float* __restrict__ sinT,
    const int* __restrict__ pos,
    unsigned short* __restrict__ qb, unsigned short* __restrict__ kb,
    unsigned short* __restrict__ vT)
{
    __shared__ __align__(16) unsigned short t[64][80];
    int b = blockIdx.x, tid = threadIdx.x;
    if (b < 8192) {
        int idx = b * 256 + tid;                 // over 2048*1024
        int s = idx >> 10, col = idx & 1023, d = col & 63;
        int p = pos[s];
        float c = cosT[p * 64 + d], sn = sinT[p * 64 + d];
        int partner = (d < 32) ? (col + 32) : (col - 32);
        float sgn = (d < 32) ? -1.f : 1.f;
        const unsigned short* row = qkv + (size_t)s * NQKV;
        float q = bf2f(row[col]), q2 = bf2f(row[partner]);
        float k = bf2f(row[Dm + col]), k2 = bf2f(row[Dm + partner]);
        qb[idx] = f2bf((q * c + sgn * q2 * sn) * 0.125f);
        kb[idx] = f2bf(k * c + sgn * k2 * sn);
    } else {
        int bb = b - 8192;                       // 512 blocks: 32 x 16
        int bs = (bb & 31) * 64, bc = (bb >> 5) * 64;
        for (int i = tid; i < 512; i += 256) {
            int r = i >> 3, c8 = (i & 7) * 8;
            *(uint4*)&t[r][c8] = *(const uint4*)(qkv + (size_t)(bs + r) * NQKV + 2048 + bc + c8);
        }
        __syncthreads();
        for (int i = tid; i < 512; i += 256) {
            int c = i >> 3, sb = (i & 7) * 8;
            alignas(16) unsigned short o[8];
#pragma unroll
            for (int jj = 0; jj < 8; ++jj) o[jj] = t[sb + jj][c];
            *(uint4*)(vT + (size_t)(bc + c) * Sq + bs + sb) = *(uint4*)o;
        }
    }
}

// ------------------------- flash attention (causal) -------------------------
__global__ __launch_bounds__(256) void attn(
    const unsigned short* __restrict__ qb, const unsigned short* __restrict__ kb,
    const unsigned short* __restrict__ vT, unsigned short* __restrict__ ob)
{
    __shared__ __align__(16) unsigned short Ks[128 * 72];
    __shared__ __align__(16) unsigned short Vs[64 * 136];
    __shared__ __align__(16) unsigned short Ps[4][16 * 136];
    int tid = threadIdx.x;
    int lane = tid & 63, wave = tid >> 6;
    int lr = lane & 15, quad = lane >> 4;
    int idx = blockIdx.x;
    int t = idx >> 4;
    int qt = (idx < 256) ? (31 - t) : (t - 16);
    int h = idx & 15;
    int q0 = qt * 64;
    const unsigned short* qp = qb + (size_t)(q0 + wave * 16 + lr) * Dm + h * 64 + quad * 8;
    bf16x8 qf0 = *(const bf16x8*)qp;
    bf16x8 qf1 = *(const bf16x8*)(qp + 32);
    f32x4 zero = {0.f, 0.f, 0.f, 0.f};
    f32x4 oacc[4];
#pragma unroll
    for (int j = 0; j < 4; ++j) oacc[j] = zero;
    float mrow[4] = {-1e30f, -1e30f, -1e30f, -1e30f};
    float lrow[4] = {0.f, 0.f, 0.f, 0.f};
    int ntile = (q0 + 64 + 127) >> 7;

    for (int kt = 0; kt < ntile; ++kt) {
        int k0 = kt << 7;
        for (int i = tid; i < 1024; i += 256) {
            int r = i >> 3, c8 = (i & 7) * 8;
            *(uint4*)(Ks + r * 72 + c8) =
                *(const uint4*)(kb + (size_t)(k0 + r) * Dm + h * 64 + c8);
        }
        for (int i = tid; i < 1024; i += 256) {
            int r = i >> 4, c8 = (i & 15) * 8;
            *(uint4*)(Vs + r * 136 + c8) =
                *(const uint4*)(vT + (size_t)(h * 64 + r) * Sq + k0 + c8);
        }
        __syncthreads();
        f32x4 sf[8];
#pragma unroll
        for (int jj = 0; jj < 8; ++jj) {
            bf16x8 kf0 = *(const bf16x8*)(Ks + (jj * 16 + lr) * 72 + quad * 8);
            bf16x8 kf1 = *(const bf16x8*)(Ks + (jj * 16 + lr) * 72 + 32 + quad * 8);
            f32x4 z = zero;
            z = __builtin_amdgcn_mfma_f32_16x16x32_bf16(qf0, kf0, z, 0, 0, 0);
            z = __builtin_amdgcn_mfma_f32_16x16x32_bf16(qf1, kf1, z, 0, 0, 0);
            sf[jj] = z;
        }
        if (kt == ntile - 1) {
#pragma unroll
            for (int jj = 0; jj < 8; ++jj)
#pragma unroll
                for (int r = 0; r < 4; ++r)
                    if (k0 + jj * 16 + lr > q0 + wave * 16 + quad * 4 + r)
                        sf[jj][r] = -1e30f;
        }
#pragma unroll
        for (int r = 0; r < 4; ++r) {
            float mx = sf[0][r];
#pragma unroll
            for (int jj = 1; jj < 8; ++jj) mx = fmaxf(mx, sf[jj][r]);
#pragma unroll
            for (int m = 1; m < 16; m <<= 1) mx = fmaxf(mx, __shfl_xor(mx, m));
            float mnew = fmaxf(mrow[r], mx);
            float alpha = __expf(mrow[r] - mnew);
            mrow[r] = mnew;
            float rs = 0.f;
#pragma unroll
            for (int jj = 0; jj < 8; ++jj) {
                float p = __expf(sf[jj][r] - mnew);
                sf[jj][r] = p; rs += p;
            }
#pragma unroll
            for (int m = 1; m < 16; m <<= 1) rs += __shfl_xor(rs, m);
            lrow[r] = lrow[r] * alpha + rs;
#pragma unroll
            for (int j = 0; j < 4; ++j) oacc[j][r] *= alpha;
        }
#pragma unroll
        for (int jj = 0; jj < 8; ++jj)
#pragma unroll
            for (int r = 0; r < 4; ++r)
                Ps[wave][(quad * 4 + r) * 136 + jj * 16 + lr] = f2bf(sf[jj][r]);
        bf16x8 pf[4];
#pragma unroll
        for (int kk = 0; kk < 4; ++kk)
            pf[kk] = *(const bf16x8*)(&Ps[wave][lr * 136 + kk * 32 + quad * 8]);
#pragma unroll
        for (int j = 0; j < 4; ++j) {
#pragma unroll
            for (int kk = 0; kk < 4; ++kk) {
                bf16x8 vf = *(const bf16x8*)(Vs + (j * 16 + lr) * 136 + kk * 32 + quad * 8);
                oacc[j] = __builtin_amdgcn_mfma_f32_16x16x32_bf16(pf[kk], vf, oacc[j], 0, 0, 0);
            }
        }
        __syncthreads();
    }
#pragma unroll
    for (int r = 0; r < 4; ++r) {
        float inv = 1.0f / lrow[r];
        int row = q0 + wave * 16 + quad * 4 + r;
#pragma unroll
        for (int j = 0; j < 4; ++j)
            ob[(size_t)row * KE2 + h * 64 + j * 16 + lr] = f2bf(oacc[j][r] * inv);
    }
}

// ---------------------------------------------------------------------------
extern "C" void kernel_launch(void* const* d_in, const int* in_sizes, int n_in,
                              void* d_out, int out_size, void* d_ws, size_t ws_size,
                              hipStream_t stream)
{
    const float* x    = (const float*)d_in[0];
    const float* nw1  = (const float*)d_in[1];
    const float* nw2  = (const float*)d_in[2];
    const float* cosT = (const float*)d_in[3];
    const float* sinT = (const float*)d_in[4];
    const int*   pos  = (const int*)d_in[5];
    const int   *qc = (const int*)d_in[6],  *kc = (const int*)d_in[10],
                *vc = (const int*)d_in[14], *oc = (const int*)d_in[18],
                *gc = (const int*)d_in[22], *uc = (const int*)d_in[26],
                *dc = (const int*)d_in[30];
    const float *qa = (const float*)d_in[7],  *ka = (const float*)d_in[11],
                *va = (const float*)d_in[15], *oa = (const float*)d_in[19],
                *ga = (const float*)d_in[23], *ua = (const float*)d_in[27],
                *da = (const float*)d_in[31];
    const float *qla = (const float*)d_in[8],  *kla = (const float*)d_in[12],
                *vla = (const float*)d_in[16], *ola = (const float*)d_in[20],
                *gla = (const float*)d_in[24], *ula = (const float*)d_in[28],
                *dla = (const float*)d_in[32];
    const float *qlb = (const float*)d_in[9],  *klb = (const float*)d_in[13],
                *vlb = (const float*)d_in[17], *olb = (const float*)d_in[21],
                *glb = (const float*)d_in[25], *ulb = (const float*)d_in[29],
                *dlb = (const float*)d_in[33];

    char* ws = (char*)d_ws;
    unsigned short* h   = (unsigned short*)(ws + 0);          // [2048,1088] bf16
    unsigned short* W   = (unsigned short*)(ws + 4456448);    // <= [5632,1056] bf16
    unsigned short* qkv = (unsigned short*)(ws + 16351232);   // [2048,3072] bf16
    unsigned short* qbf = (unsigned short*)(ws + 28934144);   // [2048,1024] bf16
    unsigned short* kbf = (unsigned short*)(ws + 33128448);   // [2048,1024] bf16
    unsigned short* vT  = (unsigned short*)(ws + 37322752);   // [1024,2048] bf16
    unsigned short* obf = (unsigned short*)(ws + 41517056);   // [2048,1056] bf16
    float*          x1  = (float*)(ws + 45842432);            // [2048,1024] f32
    unsigned short* hb  = (unsigned short*)(ws + 54231040);   // [2048,2848] bf16
    float* outp = (float*)d_out;

    // ---- attention block ----
    rmsnorm_ext<<<Sq, 256, 0, stream>>>(x, nw1, h, KE1);
    lora_T<3><<<Sq, 256, 0, stream>>>(h, KE1, Dm, qla, kla, vla, 1024, 0, 0);
    dequant_qkv<<<1632, 256, 0, stream>>>(qc, kc, vc, qa, ka, va, qlb, klb, vlb, W);
    gemm128<<<dim3(NQKV / 128, Sq / 128), 256, 0, stream>>>(h, KE1, W, KE1, KE1, qkv, NQKV);
    rope_vtrans<<<8704, 256, 0, stream>>>(qkv, cosT, sinT, pos, qbf, kbf, vT);
    attn<<<512, 256, 0, stream>>>(qbf, kbf, vT, obf);
    lora_T<1><<<Sq, 256, 0, stream>>>(obf, KE2, Dm, ola, nullptr, nullptr, 1024, 1040, 16);
    dequant_ext<<<528, 256, 0, stream>>>(oc, oa, olb, W, Dm, Dm, KE2, 1024);
    gemm64<<<dim3(Dm / 64, Sq / 128), 256, 0, stream>>>(obf, KE2, W, KE2, KE2, x1, Dm, x);
    // ---- MLP block ----
    rmsnorm_ext<<<Sq, 256, 0, stream>>>(x1, nw2, h, KE1);
    lora_T<2><<<Sq, 256, 0, stream>>>(h, KE1, Dm, gla, ula, nullptr, 1024, 0, 0);
    dequant_gu<<<2904, 256, 0, stream>>>(gc, uc, ga, ua, glb, ulb, W);
    gemm_gu<<<dim3(NGU / 128, Sq / 128), 256, 0, stream>>>(h, KE1, W, KE2, KE2, hb);
    lora_T<1><<<Sq, 256, 0, stream>>>(hb, KE3, Fm, dla, nullptr, nullptr, 2816, 2832, 16);
    dequant_ext<<<1424, 256, 0, stream>>>(dc, da, dlb, W, Dm, Fm, KE3, 2816);
    gemm64<<<dim3(Dm / 64, Sq / 128), 256, 0, stream>>>(hb, KE3, W, KE3, KE3, outp, Dm, x1);
}

// Round 5
// 544.988 us; speedup vs baseline: 1.1027x; 1.0265x over previous
//
#include <hip/hip_runtime.h>
#include <stdint.h>

// ---------------------------------------------------------------------------
// MixedSparseSingleLayerWithGate: NF4-dequant QLoRA transformer layer, MI355X.
// R5: attn rewritten barrier-free — per-wave direct-from-global K/V fragment
// loads (same 64B-segment count as staged path), V-frags prefetched before
// softmax, LDS only for wave-private P transform. o/down use 64x64-tile GEMM
// (512 blocks, 2x waves/CU vs 128x64).
// ---------------------------------------------------------------------------

#define Sq   2048
#define Dm   1024
#define Fm   2816
#define Hh   16
#define KE1  1088   // h_ext stride / qkv GEMM K   (1024 + 16*3 + 16 pad)
#define KE2  1056   // o & gate/up GEMM K          (1024 + 16 + 16)
#define KE3  2848   // down GEMM K                 (2816 + 16 + 16)
#define NQKV 3072
#define NGU  5632

typedef short bf16x8 __attribute__((ext_vector_type(8)));
typedef float f32x4  __attribute__((ext_vector_type(4)));

__constant__ float NF4_LUT[16] = {
    -1.0f, -0.6961928009986877f, -0.5250730514526367f, -0.39491748809814453f,
    -0.28444138169288635f, -0.18477343022823334f, -0.09105003625154495f, 0.0f,
    0.07958029955625534f, 0.16093020141124725f, 0.24611230194568634f,
    0.33791524171829224f, 0.44070982933044434f, 0.5626170039176941f,
    0.7229568362236023f, 1.0f};

__device__ inline unsigned short f2bf(float f) {
    union { float f; uint32_t u; } v; v.f = f;
    uint32_t u = v.u;
    return (unsigned short)((u + 0x7FFFu + ((u >> 16) & 1u)) >> 16);
}
__device__ inline float bf2f(unsigned short h) {
    union { uint32_t u; float f; } v; v.u = ((uint32_t)h) << 16;
    return v.f;
}

// async global->LDS, 16 B per lane; LDS dest = wave-uniform base + lane*16
#define GLD16(gp, lp)                                                         \
    __builtin_amdgcn_global_load_lds(                                         \
        (__attribute__((address_space(1))) void*)(uintptr_t)(gp),             \
        (__attribute__((address_space(3))) void*)(uint32_t)(uintptr_t)(lp),   \
        16, 0, 0)

// --------------------------- rmsnorm -> bf16 ext -----------------------------
__global__ __launch_bounds__(256) void rmsnorm_ext(
    const float* __restrict__ X, const float* __restrict__ W,
    unsigned short* Hout, int ldh)
{
    int s = blockIdx.x, tid = threadIdx.x;
    const float4 v = *(const float4*)(X + (size_t)s * Dm + tid * 4);
    float ss = v.x * v.x + v.y * v.y + v.z * v.z + v.w * v.w;
#pragma unroll
    for (int m = 1; m < 64; m <<= 1) ss += __shfl_xor(ss, m);
    __shared__ float red[4];
    int lane = tid & 63, wave = tid >> 6;
    if (lane == 0) red[wave] = ss;
    __syncthreads();
    float scale = rsqrtf((red[0] + red[1] + red[2] + red[3]) * (1.0f / Dm) + 1e-10f);
    const float4 w = *(const float4*)(W + tid * 4);
    alignas(8) unsigned short o[4];
    o[0] = f2bf(v.x * scale * w.x);
    o[1] = f2bf(v.y * scale * w.y);
    o[2] = f2bf(v.z * scale * w.z);
    o[3] = f2bf(v.w * scale * w.w);
    *(ushort4*)(Hout + (size_t)s * ldh + tid * 4) = *(ushort4*)o;
    if (tid < 64) Hout[(size_t)s * ldh + Dm + tid] = 0;
}

// --------------------- T = A @ la (1..3 matrices fused) ---------------------
template<int NM>
__global__ __launch_bounds__(256) void lora_T(
    const unsigned short* Aext, int lda, int K,
    const float* __restrict__ la0, const float* __restrict__ la1,
    const float* __restrict__ la2, int toff, int zoff, int zn)
{
    int s = blockIdx.x, tid = threadIdx.x;
    const float* las[3] = {la0, la1, la2};
    float acc[16 * NM];
#pragma unroll
    for (int r = 0; r < 16 * NM; ++r) acc[r] = 0.f;
    const unsigned short* arow = Aext + (size_t)s * lda;
    for (int k4 = tid * 4; k4 < K; k4 += 1024) {
        ushort4 hv = *(const ushort4*)(arow + k4);
        float hf[4] = {bf2f(hv.x), bf2f(hv.y), bf2f(hv.z), bf2f(hv.w)};
#pragma unroll
        for (int m = 0; m < NM; ++m) {
            float* a = acc + 16 * m;
#pragma unroll
            for (int e = 0; e < 4; ++e) {
                const float4* lp = (const float4*)(las[m] + (size_t)(k4 + e) * 16);
                float4 l0 = lp[0], l1 = lp[1], l2 = lp[2], l3 = lp[3];
                float h = hf[e];
                a[0]  += h * l0.x; a[1]  += h * l0.y; a[2]  += h * l0.z; a[3]  += h * l0.w;
                a[4]  += h * l1.x; a[5]  += h * l1.y; a[6]  += h * l1.z; a[7]  += h * l1.w;
                a[8]  += h * l2.x; a[9]  += h * l2.y; a[10] += h * l2.z; a[11] += h * l2.w;
                a[12] += h * l3.x; a[13] += h * l3.y; a[14] += h * l3.z; a[15] += h * l3.w;
            }
        }
    }
#pragma unroll
    for (int r = 0; r < 16 * NM; ++r)
#pragma unroll
        for (int m = 1; m < 64; m <<= 1) acc[r] += __shfl_xor(acc[r], m);
    __shared__ float red[4][16 * NM];
    int lane = tid & 63, wave = tid >> 6;
    if (lane == 0)
#pragma unroll
        for (int r = 0; r < 16 * NM; ++r) red[wave][r] = acc[r];
    __syncthreads();
    unsigned short* drow = (unsigned short*)Aext + (size_t)s * lda;
    if (tid < 16 * NM)
        drow[toff + tid] = f2bf(red[0][tid] + red[1][tid] + red[2][tid] + red[3][tid]);
    if (zn > 0 && tid >= 64 && tid < 64 + zn) drow[zoff + (tid - 64)] = 0;
}

// ---------------- NF4 dequant helpers (bf16, K-extended rows) ---------------
__device__ inline void dq_row8(const float* lut, const int* cod, const float* am,
                               const float* lb, int nr, int c8, int K, int Nlb,
                               int toff, unsigned short* out)
{
    if (c8 < K) {
        size_t base = (size_t)nr * K + c8;
        const int4* cp = (const int4*)(cod + base);
        int4 ca = cp[0], cb = cp[1];
        float a = am[base >> 6];
        out[0] = f2bf(lut[ca.x] * a); out[1] = f2bf(lut[ca.y] * a);
        out[2] = f2bf(lut[ca.z] * a); out[3] = f2bf(lut[ca.w] * a);
        out[4] = f2bf(lut[cb.x] * a); out[5] = f2bf(lut[cb.y] * a);
        out[6] = f2bf(lut[cb.z] * a); out[7] = f2bf(lut[cb.w] * a);
    } else {
        int r = c8 - toff;
#pragma unroll
        for (int i = 0; i < 8; ++i) out[i] = 0;
        if (r >= 0 && r < 16) {
#pragma unroll
            for (int i = 0; i < 8; ++i) out[i] = f2bf(lb[(size_t)(r + i) * Nlb + nr]);
        }
    }
}

// q/k/v fused: W rows [0,1024)=q, [1024,2048)=k, [2048,3072)=v ; ldw=KE1
__global__ __launch_bounds__(256) void dequant_qkv(
    const int* __restrict__ qc, const int* __restrict__ kc, const int* __restrict__ vc,
    const float* __restrict__ qa, const float* __restrict__ ka, const float* __restrict__ va,
    const float* __restrict__ qlb, const float* __restrict__ klb, const float* __restrict__ vlb,
    unsigned short* __restrict__ Wout)
{
    __shared__ float lut[16];
    if (threadIdx.x < 16) lut[threadIdx.x] = NF4_LUT[threadIdx.x];
    __syncthreads();
    int idx = blockIdx.x * 256 + threadIdx.x;        // 3072*136
    int n = idx / 136;
    int c8 = (idx - n * 136) * 8;
    int seg = n >> 10, nr = n & 1023;
    const int* cod   = (seg == 0) ? qc : (seg == 1) ? kc : vc;
    const float* am  = (seg == 0) ? qa : (seg == 1) ? ka : va;
    const float* lb  = (seg == 0) ? qlb : (seg == 1) ? klb : vlb;
    int toff = 1024 + (seg << 4);
    alignas(16) unsigned short out[8];
    dq_row8(lut, cod, am, lb, nr, c8, 1024, 1024, toff, out);
    *(uint4*)(Wout + (size_t)n * KE1 + c8) = *(uint4*)out;
}

// gate/up fused + interleaved: W row 2m = gate m (toff 1024), 2m+1 = up m (1040)
__global__ __launch_bounds__(256) void dequant_gu(
    const int* __restrict__ gc, const int* __restrict__ uc,
    const float* __restrict__ ga, const float* __restrict__ ua,
    const float* __restrict__ glb, const float* __restrict__ ulb,
    unsigned short* __restrict__ Wout)
{
    __shared__ float lut[16];
    if (threadIdx.x < 16) lut[threadIdx.x] = NF4_LUT[threadIdx.x];
    __syncthreads();
    int idx = blockIdx.x * 256 + threadIdx.x;        // 5632*132
    int n = idx / 132;
    int c8 = (idx - n * 132) * 8;
    int m = n >> 1, mat = n & 1;
    const int* cod  = mat ? uc : gc;
    const float* am = mat ? ua : ga;
    const float* lb = mat ? ulb : glb;
    int toff = 1024 + (mat << 4);
    alignas(16) unsigned short out[8];
    dq_row8(lut, cod, am, lb, m, c8, 1024, Fm, toff, out);
    *(uint4*)(Wout + (size_t)n * KE2 + c8) = *(uint4*)out;
}

// generic (o-proj, down)
__global__ __launch_bounds__(256) void dequant_ext(
    const int* __restrict__ codes, const float* __restrict__ absmax,
    const float* __restrict__ lb, unsigned short* __restrict__ Wout,
    int Nproj, int K, int ldw, int toff)
{
    __shared__ float lut[16];
    if (threadIdx.x < 16) lut[threadIdx.x] = NF4_LUT[threadIdx.x];
    __syncthreads();
    int idx = blockIdx.x * 256 + threadIdx.x;
    int cpr = ldw >> 3;
    int n = idx / cpr;
    if (n >= Nproj) return;
    int c8 = (idx - n * cpr) * 8;
    alignas(16) unsigned short out[8];
    dq_row8(lut, codes, absmax, lb, n, c8, K, Nproj, toff, out);
    *(uint4*)(Wout + (size_t)n * ldw + c8) = *(uint4*)out;
}

// ------------------- GEMM 128x128, dbuf, bf16-out (qkv) ---------------------
__global__ __launch_bounds__(256) void gemm128(
    const unsigned short* __restrict__ A, int lda,
    const unsigned short* __restrict__ B, int ldb, int K,
    unsigned short* __restrict__ Cb, int ldc)
{
    __shared__ __align__(16) unsigned short At[2][128 * 32];
    __shared__ __align__(16) unsigned short Bt[2][128 * 32];
    int tid = threadIdx.x;
    int lane = tid & 63, wave = tid >> 6;
    int lr = lane & 15, quad = lane >> 4;
    int wm = (wave >> 1) * 64, wn = (wave & 1) * 64;
    int row0 = blockIdx.y * 128, col0 = blockIdx.x * 128;
    f32x4 acc[4][4];
    f32x4 zero = {0.f, 0.f, 0.f, 0.f};
#pragma unroll
    for (int i = 0; i < 4; ++i)
#pragma unroll
        for (int j = 0; j < 4; ++j) acc[i][j] = zero;
    const unsigned short* Ag  = A + (size_t)(row0 + (tid >> 2)) * lda + (tid & 3) * 8;
    const unsigned short* Ag2 = Ag + (size_t)64 * lda;
    const unsigned short* Bg  = B + (size_t)(col0 + (tid >> 2)) * ldb + (tid & 3) * 8;
    const unsigned short* Bg2 = Bg + (size_t)64 * ldb;
    int l0 = tid * 8, l1 = (tid + 256) * 8;
    GLD16(Ag, At[0] + l0); GLD16(Ag2, At[0] + l1);
    GLD16(Bg, Bt[0] + l0); GLD16(Bg2, Bt[0] + l1);
    int nIter = K >> 5;
    for (int it = 0; it < nIter; ++it) {
        int cur = it & 1;
        __syncthreads();
        if (it + 1 < nIter) {
            int k = (it + 1) << 5, nx = cur ^ 1;
            GLD16(Ag + k, At[nx] + l0); GLD16(Ag2 + k, At[nx] + l1);
            GLD16(Bg + k, Bt[nx] + l0); GLD16(Bg2 + k, Bt[nx] + l1);
        }
        bf16x8 af[4], bfr[4];
#pragma unroll
        for (int i = 0; i < 4; ++i)
            af[i] = *(const bf16x8*)(At[cur] + (wm + i * 16 + lr) * 32 + quad * 8);
#pragma unroll
        for (int j = 0; j < 4; ++j)
            bfr[j] = *(const bf16x8*)(Bt[cur] + (wn + j * 16 + lr) * 32 + quad * 8);
#pragma unroll
        for (int i = 0; i < 4; ++i)
#pragma unroll
            for (int j = 0; j < 4; ++j)
                acc[i][j] = __builtin_amdgcn_mfma_f32_16x16x32_bf16(af[i], bfr[j], acc[i][j], 0, 0, 0);
    }
#pragma unroll
    for (int i = 0; i < 4; ++i) {
        int rowb = row0 + wm + i * 16 + quad * 4;
#pragma unroll
        for (int j = 0; j < 4; ++j) {
            int col = col0 + wn + j * 16 + lr;
#pragma unroll
            for (int r = 0; r < 4; ++r)
                Cb[(size_t)(rowb + r) * ldc + col] = f2bf(acc[i][j][r]);
        }
    }
}

// ---------------- GEMM 128x128, dbuf, SwiGLU epilogue (gate/up) -------------
// B rows interleaved g/u; out hb[row, col>>1] = u * silu(g), ld KE3
__global__ __launch_bounds__(256) void gemm_gu(
    const unsigned short* __restrict__ A, int lda,
    const unsigned short* __restrict__ B, int ldb, int K,
    unsigned short* __restrict__ Hb)
{
    __shared__ __align__(16) unsigned short At[2][128 * 32];
    __shared__ __align__(16) unsigned short Bt[2][128 * 32];
    int tid = threadIdx.x;
    int lane = tid & 63, wave = tid >> 6;
    int lr = lane & 15, quad = lane >> 4;
    int wm = (wave >> 1) * 64, wn = (wave & 1) * 64;
    int row0 = blockIdx.y * 128, col0 = blockIdx.x * 128;
    f32x4 acc[4][4];
    f32x4 zero = {0.f, 0.f, 0.f, 0.f};
#pragma unroll
    for (int i = 0; i < 4; ++i)
#pragma unroll
        for (int j = 0; j < 4; ++j) acc[i][j] = zero;
    const unsigned short* Ag  = A + (size_t)(row0 + (tid >> 2)) * lda + (tid & 3) * 8;
    const unsigned short* Ag2 = Ag + (size_t)64 * lda;
    const unsigned short* Bg  = B + (size_t)(col0 + (tid >> 2)) * ldb + (tid & 3) * 8;
    const unsigned short* Bg2 = Bg + (size_t)64 * ldb;
    int l0 = tid * 8, l1 = (tid + 256) * 8;
    GLD16(Ag, At[0] + l0); GLD16(Ag2, At[0] + l1);
    GLD16(Bg, Bt[0] + l0); GLD16(Bg2, Bt[0] + l1);
    int nIter = K >> 5;
    for (int it = 0; it < nIter; ++it) {
        int cur = it & 1;
        __syncthreads();
        if (it + 1 < nIter) {
            int k = (it + 1) << 5, nx = cur ^ 1;
            GLD16(Ag + k, At[nx] + l0); GLD16(Ag2 + k, At[nx] + l1);
            GLD16(Bg + k, Bt[nx] + l0); GLD16(Bg2 + k, Bt[nx] + l1);
        }
        bf16x8 af[4], bfr[4];
#pragma unroll
        for (int i = 0; i < 4; ++i)
            af[i] = *(const bf16x8*)(At[cur] + (wm + i * 16 + lr) * 32 + quad * 8);
#pragma unroll
        for (int j = 0; j < 4; ++j)
            bfr[j] = *(const bf16x8*)(Bt[cur] + (wn + j * 16 + lr) * 32 + quad * 8);
#pragma unroll
        for (int i = 0; i < 4; ++i)
#pragma unroll
            for (int j = 0; j < 4; ++j)
                acc[i][j] = __builtin_amdgcn_mfma_f32_16x16x32_bf16(af[i], bfr[j], acc[i][j], 0, 0, 0);
    }
#pragma unroll
    for (int i = 0; i < 4; ++i) {
        int rowb = row0 + wm + i * 16 + quad * 4;
#pragma unroll
        for (int j = 0; j < 4; ++j) {
            int col = col0 + wn + j * 16 + lr;     // even=gate, odd=up
#pragma unroll
            for (int r = 0; r < 4; ++r) {
                float own = acc[i][j][r];
                float oth = __shfl_xor(own, 1);
                if (!(lr & 1)) {                   // even lane: own=g, oth=u
                    float sig = 1.0f / (1.0f + __expf(-own));
                    Hb[(size_t)(rowb + r) * KE3 + (col >> 1)] = f2bf(oth * own * sig);
                }
            }
        }
    }
}

// --------- GEMM 64x64, dbuf, f32 + residual out (o, down; 512 blocks) -------
template<int TAG>
__global__ __launch_bounds__(256) void gemm_s(
    const unsigned short* __restrict__ A, int lda,
    const unsigned short* __restrict__ B, int ldb, int K,
    float* __restrict__ Cf, int ldc, const float* __restrict__ Radd)
{
    __shared__ __align__(16) unsigned short At[2][64 * 32];
    __shared__ __align__(16) unsigned short Bt[2][64 * 32];
    int tid = threadIdx.x;
    int lane = tid & 63, wave = tid >> 6;
    int lr = lane & 15, quad = lane >> 4;
    int row0 = blockIdx.y * 64, col0 = blockIdx.x * 64;
    f32x4 acc[4];
    f32x4 zero = {0.f, 0.f, 0.f, 0.f};
#pragma unroll
    for (int j = 0; j < 4; ++j) acc[j] = zero;
    const unsigned short* Ag = A + (size_t)(row0 + (tid >> 2)) * lda + (tid & 3) * 8;
    const unsigned short* Bg = B + (size_t)(col0 + (tid >> 2)) * ldb + (tid & 3) * 8;
    int l0 = tid * 8;
    GLD16(Ag, At[0] + l0);
    GLD16(Bg, Bt[0] + l0);
    int nIter = K >> 5;
    for (int it = 0; it < nIter; ++it) {
        int cur = it & 1;
        __syncthreads();
        if (it + 1 < nIter) {
            int k = (it + 1) << 5, nx = cur ^ 1;
            GLD16(Ag + k, At[nx] + l0);
            GLD16(Bg + k, Bt[nx] + l0);
        }
        bf16x8 af = *(const bf16x8*)(At[cur] + (wave * 16 + lr) * 32 + quad * 8);
        bf16x8 bfr[4];
#pragma unroll
        for (int j = 0; j < 4; ++j)
            bfr[j] = *(const bf16x8*)(Bt[cur] + (j * 16 + lr) * 32 + quad * 8);
#pragma unroll
        for (int j = 0; j < 4; ++j)
            acc[j] = __builtin_amdgcn_mfma_f32_16x16x32_bf16(af, bfr[j], acc[j], 0, 0, 0);
    }
    int rowb = row0 + wave * 16 + quad * 4;
#pragma unroll
    for (int j = 0; j < 4; ++j) {
        int col = col0 + j * 16 + lr;
#pragma unroll
        for (int r = 0; r < 4; ++r) {
            size_t o = (size_t)(rowb + r) * ldc + col;
            Cf[o] = acc[j][r] + Radd[o];
        }
    }
}

// ---------------- fused rope(q,k) + V-transpose ----------------------------
__global__ __launch_bounds__(256) void rope_vtrans(
    const unsigned short* __restrict__ qkv,
    const float* __restrict__ cosT, const float* __restrict__ sinT,
    const int* __restrict__ pos,
    unsigned short* __restrict__ qb, unsigned short* __restrict__ kb,
    unsigned short* __restrict__ vT)
{
    __shared__ __align__(16) unsigned short t[64][80];
    int b = blockIdx.x, tid = threadIdx.x;
    if (b < 8192) {
        int idx = b * 256 + tid;                 // over 2048*1024
        int s = idx >> 10, col = idx & 1023, d = col & 63;
        int p = pos[s];
        float c = cosT[p * 64 + d], sn = sinT[p * 64 + d];
        int partner = (d < 32) ? (col + 32) : (col - 32);
        float sgn = (d < 32) ? -1.f : 1.f;
        const unsigned short* row = qkv + (size_t)s * NQKV;
        float q = bf2f(row[col]), q2 = bf2f(row[partner]);
        float k = bf2f(row[Dm + col]), k2 = bf2f(row[Dm + partner]);
        qb[idx] = f2bf((q * c + sgn * q2 * sn) * 0.125f);
        kb[idx] = f2bf(k * c + sgn * k2 * sn);
    } else {
        int bb = b - 8192;                       // 512 blocks: 32 x 16
        int bs = (bb & 31) * 64, bc = (bb >> 5) * 64;
        for (int i = tid; i < 512; i += 256) {
            int r = i >> 3, c8 = (i & 7) * 8;
            *(uint4*)&t[r][c8] = *(const uint4*)(qkv + (size_t)(bs + r) * NQKV + 2048 + bc + c8);
        }
        __syncthreads();
        for (int i = tid; i < 512; i += 256) {
            int c = i >> 3, sb = (i & 7) * 8;
            alignas(16) unsigned short o[8];
#pragma unroll
            for (int jj = 0; jj < 8; ++jj) o[jj] = t[sb + jj][c];
            *(uint4*)(vT + (size_t)(bc + c) * Sq + bs + sb) = *(uint4*)o;
        }
    }
}

// ---------------- flash attention (causal), barrier-free --------------------
// Each wave owns 16 q rows end-to-end; K/V fragments loaded directly from
// global (16 rows x 64B contiguous per dwordx4 — same transaction count as
// staged). LDS only for the wave-private P C-layout -> A-layout transform.
__global__ __launch_bounds__(256) void attn(
    const unsigned short* __restrict__ qb, const unsigned short* __restrict__ kb,
    const unsigned short* __restrict__ vT, unsigned short* __restrict__ ob)
{
    __shared__ __align__(16) unsigned short Ps[4][16 * 136];
    int tid = threadIdx.x;
    int lane = tid & 63, wave = tid >> 6;
    int lr = lane & 15, quad = lane >> 4;
    int idx = blockIdx.x;
    int t = idx >> 4;
    int qt = (idx < 256) ? (31 - t) : (t - 16);
    int h = idx & 15;
    int r0 = qt * 64 + wave * 16;              // this wave's q-strip
    const unsigned short* qp = qb + (size_t)(r0 + lr) * Dm + h * 64 + quad * 8;
    bf16x8 qf0 = *(const bf16x8*)qp;
    bf16x8 qf1 = *(const bf16x8*)(qp + 32);
    const unsigned short* kbase = kb + h * 64 + quad * 8;
    const unsigned short* vbase = vT + (size_t)(h * 64) * Sq;
    f32x4 zero = {0.f, 0.f, 0.f, 0.f};
    f32x4 oacc[4];
#pragma unroll
    for (int j = 0; j < 4; ++j) oacc[j] = zero;
    float mrow[4] = {-1e30f, -1e30f, -1e30f, -1e30f};
    float lrow[4] = {0.f, 0.f, 0.f, 0.f};
    int ntile = (r0 + 16 + 127) >> 7;

    for (int kt = 0; kt < ntile; ++kt) {
        int k0 = kt << 7;
        // QK^T: K fragments direct from global
        f32x4 sf[8];
#pragma unroll
        for (int jj = 0; jj < 8; ++jj) {
            const unsigned short* kp = kbase + (size_t)(k0 + jj * 16 + lr) * Dm;
            bf16x8 kf0 = *(const bf16x8*)kp;
            bf16x8 kf1 = *(const bf16x8*)(kp + 32);
            f32x4 z = zero;
            z = __builtin_amdgcn_mfma_f32_16x16x32_bf16(qf0, kf0, z, 0, 0, 0);
            z = __builtin_amdgcn_mfma_f32_16x16x32_bf16(qf1, kf1, z, 0, 0, 0);
            sf[jj] = z;
        }
        // V fragments: independent of QK — issue now, latency hides behind softmax
        bf16x8 vf[4][4];
#pragma unroll
        for (int j = 0; j < 4; ++j)
#pragma unroll
            for (int kk = 0; kk < 4; ++kk)
                vf[j][kk] = *(const bf16x8*)(vbase + (size_t)(j * 16 + lr) * Sq
                                             + k0 + kk * 32 + quad * 8);
        if (kt == ntile - 1) {
#pragma unroll
            for (int jj = 0; jj < 8; ++jj)
#pragma unroll
                for (int r = 0; r < 4; ++r)
                    if (k0 + jj * 16 + lr > r0 + quad * 4 + r)
                        sf[jj][r] = -1e30f;
        }
#pragma unroll
        for (int r = 0; r < 4; ++r) {
            float mx = sf[0][r];
#pragma unroll
            for (int jj = 1; jj < 8; ++jj) mx = fmaxf(mx, sf[jj][r]);
#pragma unroll
            for (int m = 1; m < 16; m <<= 1) mx = fmaxf(mx, __shfl_xor(mx, m));
            float mnew = fmaxf(mrow[r], mx);
            float alpha = __expf(mrow[r] - mnew);
            mrow[r] = mnew;
            float rs = 0.f;
#pragma unroll
            for (int jj = 0; jj < 8; ++jj) {
                float p = __expf(sf[jj][r] - mnew);
                sf[jj][r] = p; rs += p;
            }
#pragma unroll
            for (int m = 1; m < 16; m <<= 1) rs += __shfl_xor(rs, m);
            lrow[r] = lrow[r] * alpha + rs;
#pragma unroll
            for (int j = 0; j < 4; ++j) oacc[j][r] *= alpha;
        }
        // P: C-layout -> wave-private LDS -> A-layout frags (no barrier needed)
#pragma unroll
        for (int jj = 0; jj < 8; ++jj)
#pragma unroll
            for (int r = 0; r < 4; ++r)
                Ps[wave][(quad * 4 + r) * 136 + jj * 16 + lr] = f2bf(sf[jj][r]);
        bf16x8 pf[4];
#pragma unroll
        for (int kk = 0; kk < 4; ++kk)
            pf[kk] = *(const bf16x8*)(&Ps[wave][lr * 136 + kk * 32 + quad * 8]);
#pragma unroll
        for (int j = 0; j < 4; ++j)
#pragma unroll
            for (int kk = 0; kk < 4; ++kk)
                oacc[j] = __builtin_amdgcn_mfma_f32_16x16x32_bf16(pf[kk], vf[j][kk], oacc[j], 0, 0, 0);
    }
#pragma unroll
    for (int r = 0; r < 4; ++r) {
        float inv = 1.0f / lrow[r];
        int row = r0 + quad * 4 + r;
#pragma unroll
        for (int j = 0; j < 4; ++j)
            ob[(size_t)row * KE2 + h * 64 + j * 16 + lr] = f2bf(oacc[j][r] * inv);
    }
}

// ---------------------------------------------------------------------------
extern "C" void kernel_launch(void* const* d_in, const int* in_sizes, int n_in,
                              void* d_out, int out_size, void* d_ws, size_t ws_size,
                              hipStream_t stream)
{
    const float* x    = (const float*)d_in[0];
    const float* nw1  = (const float*)d_in[1];
    const float* nw2  = (const float*)d_in[2];
    const float* cosT = (const float*)d_in[3];
    const float* sinT = (const float*)d_in[4];
    const int*   pos  = (const int*)d_in[5];
    const int   *qc = (const int*)d_in[6],  *kc = (const int*)d_in[10],
                *vc = (const int*)d_in[14], *oc = (const int*)d_in[18],
                *gc = (const int*)d_in[22], *uc = (const int*)d_in[26],
                *dc = (const int*)d_in[30];
    const float *qa = (const float*)d_in[7],  *ka = (const float*)d_in[11],
                *va = (const float*)d_in[15], *oa = (const float*)d_in[19],
                *ga = (const float*)d_in[23], *ua = (const float*)d_in[27],
                *da = (const float*)d_in[31];
    const float *qla = (const float*)d_in[8],  *kla = (const float*)d_in[12],
                *vla = (const float*)d_in[16], *ola = (const float*)d_in[20],
                *gla = (const float*)d_in[24], *ula = (const float*)d_in[28],
                *dla = (const float*)d_in[32];
    const float *qlb = (const float*)d_in[9],  *klb = (const float*)d_in[13],
                *vlb = (const float*)d_in[17], *olb = (const float*)d_in[21],
                *glb = (const float*)d_in[25], *ulb = (const float*)d_in[29],
                *dlb = (const float*)d_in[33];

    char* ws = (char*)d_ws;
    unsigned short* h   = (unsigned short*)(ws + 0);          // [2048,1088] bf16
    unsigned short* W   = (unsigned short*)(ws + 4456448);    // <= [5632,1056] bf16
    unsigned short* qkv = (unsigned short*)(ws + 16351232);   // [2048,3072] bf16
    unsigned short* qbf = (unsigned short*)(ws + 28934144);   // [2048,1024] bf16
    unsigned short* kbf = (unsigned short*)(ws + 33128448);   // [2048,1024] bf16
    unsigned short* vT  = (unsigned short*)(ws + 37322752);   // [1024,2048] bf16
    unsigned short* obf = (unsigned short*)(ws + 41517056);   // [2048,1056] bf16
    float*          x1  = (float*)(ws + 45842432);            // [2048,1024] f32
    unsigned short* hb  = (unsigned short*)(ws + 54231040);   // [2048,2848] bf16
    float* outp = (float*)d_out;

    // ---- attention block ----
    rmsnorm_ext<<<Sq, 256, 0, stream>>>(x, nw1, h, KE1);
    lora_T<3><<<Sq, 256, 0, stream>>>(h, KE1, Dm, qla, kla, vla, 1024, 0, 0);
    dequant_qkv<<<1632, 256, 0, stream>>>(qc, kc, vc, qa, ka, va, qlb, klb, vlb, W);
    gemm128<<<dim3(NQKV / 128, Sq / 128), 256, 0, stream>>>(h, KE1, W, KE1, KE1, qkv, NQKV);
    rope_vtrans<<<8704, 256, 0, stream>>>(qkv, cosT, sinT, pos, qbf, kbf, vT);
    attn<<<512, 256, 0, stream>>>(qbf, kbf, vT, obf);
    lora_T<1><<<Sq, 256, 0, stream>>>(obf, KE2, Dm, ola, nullptr, nullptr, 1024, 1040, 16);
    dequant_ext<<<528, 256, 0, stream>>>(oc, oa, olb, W, Dm, Dm, KE2, 1024);
    gemm_s<0><<<dim3(Dm / 64, Sq / 64), 256, 0, stream>>>(obf, KE2, W, KE2, KE2, x1, Dm, x);
    // ---- MLP block ----
    rmsnorm_ext<<<Sq, 256, 0, stream>>>(x1, nw2, h, KE1);
    lora_T<2><<<Sq, 256, 0, stream>>>(h, KE1, Dm, gla, ula, nullptr, 1024, 0, 0);
    dequant_gu<<<2904, 256, 0, stream>>>(gc, uc, ga, ua, glb, ulb, W);
    gemm_gu<<<dim3(NGU / 128, Sq / 128), 256, 0, stream>>>(h, KE1, W, KE2, KE2, hb);
    lora_T<1><<<Sq, 256, 0, stream>>>(hb, KE3, Fm, dla, nullptr, nullptr, 2816, 2832, 16);
    dequant_ext<<<1424, 256, 0, stream>>>(dc, da, dlb, W, Dm, Fm, KE3, 2816);
    gemm_s<1><<<dim3(Dm / 64, Sq / 64), 256, 0, stream>>>(hb, KE3, W, KE3, KE3, outp, Dm, x1);
}